// Round 4
// baseline (626.097 us; speedup 1.0000x reference)
//
#include <hip/hip_runtime.h>
#include <cstddef>

#define PI_F 3.14159265358979323846f
#define TWO_PI_32 0.19634954084936207f   // 2*pi/32

#define NCH 256   // C
#define NB  32    // B
#define NF  544   // n*(n/2+1)
#define FPC 272   // freqs per A-chunk (2 chunks)

typedef short  bf16x8 __attribute__((ext_vector_type(8)));
typedef float  f32x4  __attribute__((ext_vector_type(4)));

// ---- workspace layout (bytes) ----
// p-plane ordering: p = j*32 + i  (j=0..16, i=0..31)
#define SZ_AFRAG ((size_t)FPC*8*16*2*1024)      // 71,303,168
#define SZ_TST   ((size_t)17*8192*64*2)         // 17,825,792 per plane (hi or lo)
#define SZ_P32   ((size_t)NF*8192*4)            // 17,825,792 (fp32 plane [p][bc])
#define SZ_PB    ((size_t)NF*8192*2)            // 8,912,896  (bf16 plane [p][bc])
#define SZ_WXH   ((size_t)NF*8192*8)            // 35,651,584 (float2 [p][ob])
#define OFF_AFRAG ((size_t)0)
#define OFF_TH   (OFF_AFRAG + SZ_AFRAG)          // Tst hi ; later Yst hi
#define OFF_TL   (OFF_TH + SZ_TST)               // Tst lo ; later Yst lo
#define OFF_Z32R (OFF_TL + SZ_TST)               // z32 real ; later Gr
#define OFF_Z32I (OFF_Z32R + SZ_P32)             // z32 imag ; later Gi
#define OFF_ZBR  (OFF_Z32I + SZ_P32)             // z bf16 real ; reused as wx real
#define OFF_ZBI  (OFF_ZBR + SZ_PB)
#define OFF_TBR  (OFF_ZBI + SZ_PB)
#define OFF_TBI  (OFF_TBR + SZ_PB)
#define OFF_WXH  (OFF_TBI + SZ_PB)
#define OFF_HFRAG (OFF_WXH + SZ_WXH)
#define SZ_HFRAG ((size_t)8*16*1024)
#define OFF_RED  (OFF_HFRAG + SZ_HFRAG)
#define WS_NEED  (OFF_RED + (size_t)4096)        // ~214.0 MB (< 214.18 MB proven in R1)

__device__ __forceinline__ unsigned short f2bf(float x) {
    unsigned int u = __float_as_uint(x);
    u += 0x7FFFu + ((u >> 16) & 1u);            // RNE
    return (unsigned short)(u >> 16);
}
__device__ __forceinline__ float bf2f(unsigned short h) {
    return __uint_as_float((unsigned int)h << 16);
}
__device__ __forceinline__ unsigned int pack2(float a, float b) {
    return (unsigned int)f2bf(a) | ((unsigned int)f2bf(b) << 16);
}
__device__ __forceinline__ uint4 pk8(const unsigned short* h) {
    return make_uint4((unsigned)h[0] | ((unsigned)h[1]<<16),
                      (unsigned)h[2] | ((unsigned)h[3]<<16),
                      (unsigned)h[4] | ((unsigned)h[5]<<16),
                      (unsigned)h[6] | ((unsigned)h[7]<<16));
}

// ---------------- norm of wfft (closed form via Parseval) ----------------
__global__ void norm_part(const float* __restrict__ w, float* __restrict__ red) {
    int idx = blockIdx.x * 256 + threadIdx.x;
    const float* wp = w + (size_t)idx * 9;
    float s2 = 0.f, aa = 0.f, bb = 0.f;
#pragma unroll
    for (int u = 0; u < 3; u++) {
        float w0 = wp[u*3+0], w1 = wp[u*3+1], w2 = wp[u*3+2];
        s2 += w0*w0 + w1*w1 + w2*w2;
        float au = w0 + w1 + w2, bu = w0 - w1 + w2;
        aa += au*au; bb += bu*bu;
    }
    float p = 512.f*s2 + 16.f*(aa + bb);
    __shared__ float sm[256];
    sm[threadIdx.x] = p; __syncthreads();
    for (int s = 128; s > 0; s >>= 1) {
        if (threadIdx.x < s) sm[threadIdx.x] += sm[threadIdx.x + s];
        __syncthreads();
    }
    if (threadIdx.x == 0) red[blockIdx.x] = sm[0];
}

__global__ void norm_final(const float* __restrict__ red, const float* __restrict__ alpha,
                           float* __restrict__ sig) {
    __shared__ float sm[256];
    sm[threadIdx.x] = red[threadIdx.x]; __syncthreads();
    for (int s = 128; s > 0; s >>= 1) {
        if (threadIdx.x < s) sm[threadIdx.x] += sm[threadIdx.x + s];
        __syncthreads();
    }
    if (threadIdx.x == 0) sig[0] = alpha[0] / sqrtf(sm[0]);
}

// ---------------- H fragments (A-operand: m=o, k=c) ----------------
__global__ void hfrag_build(const float* __restrict__ H, unsigned short* __restrict__ Hfrag) {
    int kk = blockIdx.x, mt = blockIdx.y, lane = threadIdx.x;   // 64 threads
    int o = mt*16 + (lane & 15), c0 = kk*32 + (lane >> 4)*8;
    const float* hp = H + (size_t)o*NCH + c0;
    uint4 u;
    u.x = pack2(hp[0], hp[1]); u.y = pack2(hp[2], hp[3]);
    u.z = pack2(hp[4], hp[5]); u.w = pack2(hp[6], hp[7]);
    ((uint4*)Hfrag)[((size_t)kk*16 + mt)*64 + lane] = u;
}

// ---------------- F1: s->j DFT via MFMA.  x -> Tst[j][bc][k64] hi/lo ----------------
// Tst k-layout: k=0..31 -> Tr[r=k],  k=32..63 -> Ti[r=k-32]  (Ti = -sum x sin)
__global__ __launch_bounds__(256) void fft1_mfma(const float* __restrict__ x,
        unsigned short* __restrict__ Th, unsigned short* __restrict__ Tl)
{
    __shared__ unsigned short xh[8*1024], xl[8*1024];   // 16KB each, swizzled
    int t = threadIdx.x;
    int bc0 = blockIdx.x * 8;
    const float* xp = x + (size_t)bc0 * 1024;
#pragma unroll
    for (int it = 0; it < 8; it++) {
        int idx = (it*256 + t) * 4;
        float4 v = *(const float4*)(xp + idx);
        int bcl = idx >> 10, rem = idx & 1023, r = rem >> 5, s = rem & 31;
        float vv[4] = {v.x, v.y, v.z, v.w};
        unsigned short h[4], l[4];
#pragma unroll
        for (int q = 0; q < 4; q++) {
            h[q] = f2bf(vv[q]);
            l[q] = f2bf(vv[q] - bf2f(h[q]));
        }
        int sblk = s & ~7, soff = s & 7;
        int base = (bcl*32 + r)*64 + (((sblk*2) ^ ((((r>>1)&3)) << 4)) + soff*2);
        *(uint2*)((char*)xh + base) = make_uint2((unsigned)h[0] | ((unsigned)h[1]<<16),
                                                 (unsigned)h[2] | ((unsigned)h[3]<<16));
        *(uint2*)((char*)xl + base) = make_uint2((unsigned)l[0] | ((unsigned)l[1]<<16),
                                                 (unsigned)l[2] | ((unsigned)l[3]<<16));
    }
    // twiddle B-frags: cols 0..16 = cos(2pi j s/32); 17..33 = -sin; 34..47 = 0
    int l6 = t & 63, lo15 = l6 & 15, khi = l6 >> 4;
    bf16x8 Bh[3], Bl[3];
#pragma unroll
    for (int nt = 0; nt < 3; nt++) {
        int jcol = nt*16 + lo15;
        unsigned short hh[8], ll[8];
#pragma unroll
        for (int e = 0; e < 8; e++) {
            int s = khi*8 + e;
            float v = 0.f;
            if (jcol <= 16)      v =  cosf(TWO_PI_32 * (float)((jcol * s) & 31));
            else if (jcol <= 33) v = -sinf(TWO_PI_32 * (float)(((jcol - 17) * s) & 31));
            hh[e] = f2bf(v); ll[e] = f2bf(v - bf2f(hh[e]));
        }
        uint4 uh = pk8(hh), ul = pk8(ll);
        Bh[nt] = __builtin_bit_cast(bf16x8, uh);
        Bl[nt] = __builtin_bit_cast(bf16x8, ul);
    }
    __syncthreads();
    int w = t >> 6;
#pragma unroll
    for (int q = 0; q < 4; q++) {
        int mt = w + q*4;
        int bcl = mt >> 1, rbase = (mt & 1)*16;
        int r = rbase + lo15;
        int ab = (bcl*32 + r)*64 + (((khi*8)*2) ^ (((r>>1)&3) << 4));
        bf16x8 Ah_ = *(bf16x8*)((char*)xh + ab);
        bf16x8 Al_ = *(bf16x8*)((char*)xl + ab);
#pragma unroll
        for (int nt = 0; nt < 3; nt++) {
            f32x4 acc = {0.f,0.f,0.f,0.f};
            acc = __builtin_amdgcn_mfma_f32_16x16x32_bf16(Ah_, Bh[nt], acc, 0,0,0);
            acc = __builtin_amdgcn_mfma_f32_16x16x32_bf16(Al_, Bh[nt], acc, 0,0,0);
            acc = __builtin_amdgcn_mfma_f32_16x16x32_bf16(Ah_, Bl[nt], acc, 0,0,0);
            int jcol = nt*16 + lo15;
            if (jcol < 34) {
                int j   = (jcol <= 16) ? jcol : jcol - 17;
                int seg = (jcol <= 16) ? 0 : 32;
                int r0  = rbase + khi*4;
                size_t dst = ((size_t)j*8192 + bc0 + bcl)*64 + seg + r0;
                unsigned short h0 = f2bf(acc[0]), h1 = f2bf(acc[1]),
                               h2 = f2bf(acc[2]), h3 = f2bf(acc[3]);
                *(uint2*)(Th + dst) = make_uint2((unsigned)h0 | ((unsigned)h1<<16),
                                                 (unsigned)h2 | ((unsigned)h3<<16));
                unsigned short g0 = f2bf(acc[0]-bf2f(h0)), g1 = f2bf(acc[1]-bf2f(h1)),
                               g2 = f2bf(acc[2]-bf2f(h2)), g3 = f2bf(acc[3]-bf2f(h3));
                *(uint2*)(Tl + dst) = make_uint2((unsigned)g0 | ((unsigned)g1<<16),
                                                 (unsigned)g2 | ((unsigned)g3<<16));
            }
        }
    }
}

// ---------------- F2: r->i DFT via MFMA.  Tst -> z planes [p][bc] ----------------
__global__ __launch_bounds__(256) void fft2_mfma(
    const unsigned short* __restrict__ Th, const unsigned short* __restrict__ Tl,
    float* __restrict__ z32r, float* __restrict__ z32i,
    unsigned short* __restrict__ zbr, unsigned short* __restrict__ zbi)
{
    __shared__ unsigned short Ah[128*64], Al[128*64];   // 16KB each, swizzled
    int t = threadIdx.x;
    int bct = blockIdx.x, j = blockIdx.y;
    const unsigned short* sh = Th + ((size_t)j*8192 + bct*128)*64;
    const unsigned short* sl = Tl + ((size_t)j*8192 + bct*128)*64;
#pragma unroll
    for (int it = 0; it < 4; it++) {
        int u = it*256 + t;
        int bcl = u >> 3, ku = u & 7;
        int lb = bcl*128 + ((ku*16) ^ ((bcl&7)<<4));
        *(uint4*)((char*)Ah + lb) = *(const uint4*)(sh + (size_t)bcl*64 + ku*8);
        *(uint4*)((char*)Al + lb) = *(const uint4*)(sl + (size_t)bcl*64 + ku*8);
    }
    // twiddle B: cols 0..31 = zr(i), 32..63 = zi(i); k<32 acts on Tr, k>=32 on Ti
    int l6 = t & 63, lo15 = l6 & 15, khi = l6 >> 4;
    bf16x8 Bh[8], Bl[8];
#pragma unroll
    for (int nt = 0; nt < 4; nt++) {
#pragma unroll
        for (int kst = 0; kst < 2; kst++) {
            int icol = nt*16 + lo15;
            int ii = icol & 31; bool zrow = icol < 32;
            unsigned short hh[8], ll[8];
#pragma unroll
            for (int e = 0; e < 8; e++) {
                int k = kst*32 + khi*8 + e;
                int r = k & 31; bool kre = k < 32;
                float ang = TWO_PI_32 * (float)((ii * r) & 31);
                float cv = cosf(ang), sv = sinf(ang);
                float v = zrow ? (kre ? cv : sv) : (kre ? -sv : cv);
                hh[e] = f2bf(v); ll[e] = f2bf(v - bf2f(hh[e]));
            }
            uint4 uh = pk8(hh), ul = pk8(ll);
            Bh[nt*2+kst] = __builtin_bit_cast(bf16x8, uh);
            Bl[nt*2+kst] = __builtin_bit_cast(bf16x8, ul);
        }
    }
    __syncthreads();
    int w = t >> 6;
#pragma unroll
    for (int q = 0; q < 2; q++) {
        int mt = w*2 + q;
        int bcl = mt*16 + lo15;
        bf16x8 Fh[2], Fl[2];
#pragma unroll
        for (int kst = 0; kst < 2; kst++) {
            int kb = (kst*32 + khi*8)*2;
            int ab = bcl*128 + (kb ^ ((bcl&7)<<4));
            Fh[kst] = *(bf16x8*)((char*)Ah + ab);
            Fl[kst] = *(bf16x8*)((char*)Al + ab);
        }
#pragma unroll
        for (int nt = 0; nt < 4; nt++) {
            f32x4 acc = {0.f,0.f,0.f,0.f};
#pragma unroll
            for (int kst = 0; kst < 2; kst++) {
                acc = __builtin_amdgcn_mfma_f32_16x16x32_bf16(Fh[kst], Bh[nt*2+kst], acc, 0,0,0);
                acc = __builtin_amdgcn_mfma_f32_16x16x32_bf16(Fl[kst], Bh[nt*2+kst], acc, 0,0,0);
                acc = __builtin_amdgcn_mfma_f32_16x16x32_bf16(Fh[kst], Bl[nt*2+kst], acc, 0,0,0);
            }
            int icol = nt*16 + lo15;
            int p = j*32 + (icol & 31);
            int bc = bct*128 + mt*16 + khi*4;
            size_t zb = (size_t)p*8192 + bc;
            float* z32 = (icol < 32) ? z32r : z32i;
            unsigned short* zb16 = (icol < 32) ? zbr : zbi;
            *(float4*)(z32 + zb) = make_float4(acc[0], acc[1], acc[2], acc[3]);
            *(uint2*)(zb16 + zb) = make_uint2(pack2(acc[0],acc[1]), pack2(acc[2],acc[3]));
        }
    }
}

// ---------------- A-build into MFMA fragment order (table-lookup form) ----------------
// A[c,cp] = sigma * sum_q [ (w1-w2)_q * Re(P_q) + i (w1+w2)_q * Im(P_q) ],
// P_q = wtab[(i*(1-u) + j*(1-v)) & 31],  wtab[t] = e^{-2pi i t/32}
__global__ __launch_bounds__(256) void a_build_frag(const float* __restrict__ w,
        const float* __restrict__ sig, unsigned short* __restrict__ Afrag, int f0)
{
    __shared__ float2 wtab[32];
    __shared__ unsigned short lar[512], lai[512];
    int t = threadIdx.x;
    if (t < 32) {
        float ph = -2.f * PI_F * (float)t / 32.f;
        wtab[t] = make_float2(cosf(ph), sinf(ph));
    }
    int mt = blockIdx.x, kk = blockIdx.y, fs = blockIdx.z;
    int c = mt*16 + (t & 15), cpl = t >> 4;
    int cpA = kk*32 + cpl, cpB = cpA + 16;
    float ua[9], va[9], ub[9], vb[9];
    {
        const float* pa1 = w + ((size_t)c*NCH + cpA)*9;
        const float* pb1 = w + ((size_t)c*NCH + cpB)*9;
        const float* pa2 = w + ((size_t)cpA*NCH + c)*9;
        const float* pb2 = w + ((size_t)cpB*NCH + c)*9;
#pragma unroll
        for (int q = 0; q < 9; q++) {
            float w1a = pa1[q], w2a = pa2[q], w1b = pb1[q], w2b = pb2[q];
            ua[q] = w1a - w2a; va[q] = w1a + w2a;
            ub[q] = w1b - w2b; vb[q] = w1b + w2b;
        }
    }
    float s = sig[0];
    int la_ = ((c & 15) + 16*(cpl>>3))*8 + (cpl & 7);
    int lb_ = la_ + 32*8;
    __syncthreads();
    for (int fl = fs*68; fl < fs*68 + 68; fl++) {
        int p = f0 + fl;
        int i = p & 31, jj = p >> 5;
        int m_[9];
        m_[0] = (i + jj) & 31;  m_[1] = i;             m_[2] = (i - jj) & 31;
        m_[3] = jj;             m_[4] = 0;             m_[5] = (32 - jj) & 31;
        m_[6] = (jj - i) & 31;  m_[7] = (32 - i) & 31; m_[8] = (64 - i - jj) & 31;
        float ArA = 0.f, AiA = 0.f, ArB = 0.f, AiB = 0.f;
#pragma unroll
        for (int q = 0; q < 9; q++) {
            float2 P = wtab[m_[q]];
            ArA += ua[q] * P.x; AiA += va[q] * P.y;
            ArB += ub[q] * P.x; AiB += vb[q] * P.y;
        }
        lar[la_] = f2bf(s*ArA); lai[la_] = f2bf(s*AiA);
        lar[lb_] = f2bf(s*ArB); lai[lb_] = f2bf(s*AiB);
        __syncthreads();
        size_t bch = (((size_t)fl*8 + kk)*16 + mt)*256;   // uint2 units
        ((uint2*)Afrag)[bch + t] = (t < 128) ? ((const uint2*)lar)[t]
                                             : ((const uint2*)lai)[t - 128];
        __syncthreads();
    }
}

// ---------------- Neumann pass via MFMA ----------------
// MODE 1: out = z32 - acc   (t = z - A z)
// MODE 2: out = z32 - 2*acc (wx = z - 2 A t)
template<int MODE>
__global__ __launch_bounds__(256) void neum_pass(
    const unsigned short* __restrict__ Afrag,
    const unsigned short* __restrict__ BR, const unsigned short* __restrict__ BI,
    const float* __restrict__ z32r, const float* __restrict__ z32i,
    unsigned short* __restrict__ outR, unsigned short* __restrict__ outI, int f0)
{
    __shared__ uint4 lz[2][1024];   // 32 KB, swizzled
    int fl = blockIdx.x >> 1, half = blockIdx.x & 1;
    int f = f0 + fl;
    int t = threadIdx.x;
    const uint4* s0 = (const uint4*)(BR + (size_t)f*8192);
    const uint4* s1 = (const uint4*)(BI + (size_t)f*8192);
    for (int u = t; u < 1024; u += 256) {
        int b = u >> 5, o16 = u & 31;
        int du = b*32 + (o16 ^ (b & 7));
        lz[0][du] = s0[u];
        lz[1][du] = s1[u];
    }
    __syncthreads();
    int w = t >> 6, lane = t & 63, lo = lane & 15, hi = lane >> 4;
    f32x4 accr[2][2], acci[2][2];
    f32x4 zz = {0.f, 0.f, 0.f, 0.f};
#pragma unroll
    for (int mt = 0; mt < 2; mt++)
#pragma unroll
        for (int nt = 0; nt < 2; nt++) { accr[mt][nt] = zz; acci[mt][nt] = zz; }
    const uint4* A4 = (const uint4*)Afrag;
    for (int kk = 0; kk < 8; kk++) {
        bf16x8 ar[2], ai[2], ain[2];
#pragma unroll
        for (int mt = 0; mt < 2; mt++) {
            int mtg = half*8 + w*2 + mt;
            size_t idx = ((((size_t)fl*8 + kk)*16 + mtg)*2)*64 + lane;
            uint4 va = A4[idx], vb = A4[idx + 64];
            ar[mt] = __builtin_bit_cast(bf16x8, va);
            ai[mt] = __builtin_bit_cast(bf16x8, vb);
            uint4 vn = make_uint4(vb.x ^ 0x80008000u, vb.y ^ 0x80008000u,
                                  vb.z ^ 0x80008000u, vb.w ^ 0x80008000u);
            ain[mt] = __builtin_bit_cast(bf16x8, vn);
        }
        bf16x8 zr[2], zi_[2];
#pragma unroll
        for (int nt = 0; nt < 2; nt++) {
            int b = nt*16 + lo;
            int du = b*32 + ((kk*4 + hi) ^ (b & 7));
            zr[nt]  = __builtin_bit_cast(bf16x8, lz[0][du]);
            zi_[nt] = __builtin_bit_cast(bf16x8, lz[1][du]);
        }
#pragma unroll
        for (int mt = 0; mt < 2; mt++)
#pragma unroll
            for (int nt = 0; nt < 2; nt++) {
                accr[mt][nt] = __builtin_amdgcn_mfma_f32_16x16x32_bf16(ar[mt],  zr[nt],  accr[mt][nt], 0, 0, 0);
                accr[mt][nt] = __builtin_amdgcn_mfma_f32_16x16x32_bf16(ain[mt], zi_[nt], accr[mt][nt], 0, 0, 0);
                acci[mt][nt] = __builtin_amdgcn_mfma_f32_16x16x32_bf16(ar[mt],  zi_[nt], acci[mt][nt], 0, 0, 0);
                acci[mt][nt] = __builtin_amdgcn_mfma_f32_16x16x32_bf16(ai[mt],  zr[nt],  acci[mt][nt], 0, 0, 0);
            }
    }
#pragma unroll
    for (int mt = 0; mt < 2; mt++)
#pragma unroll
        for (int nt = 0; nt < 2; nt++) {
            int c0 = half*128 + w*32 + mt*16 + hi*4;
            int b  = nt*16 + lo;
            size_t zb = ((size_t)f*NB + b)*NCH + c0;
            float vr[4], vi[4];
#pragma unroll
            for (int jj = 0; jj < 4; jj++) {
                float zrv = z32r[zb + jj], ziv = z32i[zb + jj];
                float cr = accr[mt][nt][jj], ci = acci[mt][nt][jj];
                if (MODE == 1) { vr[jj] = zrv - cr;      vi[jj] = ziv - ci; }
                else           { vr[jj] = zrv - 2.f*cr;  vi[jj] = ziv - 2.f*ci; }
            }
            *(uint2*)(outR + zb) = make_uint2(pack2(vr[0], vr[1]), pack2(vr[2], vr[3]));
            *(uint2*)(outI + zb) = make_uint2(pack2(vi[0], vi[1]), pack2(vi[2], vi[3]));
        }
}

// ---------------- H pass via MFMA: wxh[p][o*32+b] = sum_c H[o,c] wx[p,c,b] ----------------
__global__ __launch_bounds__(256) void pass_h(
    const unsigned short* __restrict__ Hfrag,
    const unsigned short* __restrict__ BR, const unsigned short* __restrict__ BI,
    float2* __restrict__ wxh, int f0)
{
    __shared__ uint4 lz[2][1024];
    int fl = blockIdx.x >> 1, half = blockIdx.x & 1;
    int f = f0 + fl;
    int t = threadIdx.x;
    const uint4* s0 = (const uint4*)(BR + (size_t)f*8192);
    const uint4* s1 = (const uint4*)(BI + (size_t)f*8192);
    for (int u = t; u < 1024; u += 256) {
        int b = u >> 5, o16 = u & 31;
        int du = b*32 + (o16 ^ (b & 7));
        lz[0][du] = s0[u];
        lz[1][du] = s1[u];
    }
    __syncthreads();
    int w = t >> 6, lane = t & 63, lo = lane & 15, hi = lane >> 4;
    f32x4 accr[2][2], acci[2][2];
    f32x4 zz = {0.f, 0.f, 0.f, 0.f};
#pragma unroll
    for (int mt = 0; mt < 2; mt++)
#pragma unroll
        for (int nt = 0; nt < 2; nt++) { accr[mt][nt] = zz; acci[mt][nt] = zz; }
    const uint4* H4 = (const uint4*)Hfrag;
    for (int kk = 0; kk < 8; kk++) {
        bf16x8 hm[2];
#pragma unroll
        for (int mt = 0; mt < 2; mt++) {
            int mtg = half*8 + w*2 + mt;
            hm[mt] = __builtin_bit_cast(bf16x8, H4[((size_t)kk*16 + mtg)*64 + lane]);
        }
        bf16x8 zr[2], zi_[2];
#pragma unroll
        for (int nt = 0; nt < 2; nt++) {
            int b = nt*16 + lo;
            int du = b*32 + ((kk*4 + hi) ^ (b & 7));
            zr[nt]  = __builtin_bit_cast(bf16x8, lz[0][du]);
            zi_[nt] = __builtin_bit_cast(bf16x8, lz[1][du]);
        }
#pragma unroll
        for (int mt = 0; mt < 2; mt++)
#pragma unroll
            for (int nt = 0; nt < 2; nt++) {
                accr[mt][nt] = __builtin_amdgcn_mfma_f32_16x16x32_bf16(hm[mt], zr[nt],  accr[mt][nt], 0, 0, 0);
                acci[mt][nt] = __builtin_amdgcn_mfma_f32_16x16x32_bf16(hm[mt], zi_[nt], acci[mt][nt], 0, 0, 0);
            }
    }
#pragma unroll
    for (int mt = 0; mt < 2; mt++)
#pragma unroll
        for (int nt = 0; nt < 2; nt++) {
            int o0 = half*128 + w*32 + mt*16 + hi*4;
            int b  = nt*16 + lo;
#pragma unroll
            for (int jj = 0; jj < 4; jj++) {
                wxh[((size_t)f*NCH + o0 + jj)*NB + b] =
                    make_float2(accr[mt][nt][jj], acci[mt][nt][jj]);
            }
        }
}

// ---------------- transpose wxh[p][ob] -> Yst[j][ob][k64] hi/lo ----------------
// k=0..31 -> Yr[i=k], k=32..63 -> Yi[i=k-32]
__global__ __launch_bounds__(256) void transpose_y(const float2* __restrict__ wxh,
        unsigned short* __restrict__ Yh, unsigned short* __restrict__ Yl)
{
    __shared__ float2 tile[32][129];
    int t = threadIdx.x, obt = blockIdx.x, j = blockIdx.y;
#pragma unroll
    for (int it = 0; it < 16; it++) {
        int u = it*256 + t; int i = u >> 7, obl = u & 127;
        tile[i][obl] = wxh[((size_t)(j*32 + i))*8192 + obt*128 + obl];
    }
    __syncthreads();
#pragma unroll
    for (int it = 0; it < 4; it++) {          // FIX: was 8 -> OOB reads + cross-block write race
        int u = it*256 + t; int obl = u >> 3, kb = u & 7;
        unsigned short hh[8], ll[8];
#pragma unroll
        for (int qq = 0; qq < 8; qq++) {
            int kk = kb*8 + qq; int i = kk & 31;
            float2 v2 = tile[i][obl];
            float v = (kk < 32) ? v2.x : v2.y;
            hh[qq] = f2bf(v); ll[qq] = f2bf(v - bf2f(hh[qq]));
        }
        size_t dst = ((size_t)j*8192 + obt*128 + obl)*64 + kb*8;
        *(uint4*)(Yh + dst) = pk8(hh);
        *(uint4*)(Yl + dst) = pk8(ll);
    }
}

// ---------------- inverse i-DFT via MFMA: Yst -> Gr/Gi fp32 [j][ob][r] ----------------
__global__ __launch_bounds__(256) void ifft_i_mfma(
    const unsigned short* __restrict__ Yh, const unsigned short* __restrict__ Yl,
    float* __restrict__ Gr, float* __restrict__ Gi)
{
    __shared__ unsigned short Dh_[128*64], Dl_[128*64];
    int t = threadIdx.x;
    int obt = blockIdx.x, j = blockIdx.y;
    const unsigned short* sh = Yh + ((size_t)j*8192 + obt*128)*64;
    const unsigned short* sl = Yl + ((size_t)j*8192 + obt*128)*64;
#pragma unroll
    for (int it = 0; it < 4; it++) {
        int u = it*256 + t;
        int obl = u >> 3, ku = u & 7;
        int lb = obl*128 + ((ku*16) ^ ((obl&7)<<4));
        *(uint4*)((char*)Dh_ + lb) = *(const uint4*)(sh + (size_t)obl*64 + ku*8);
        *(uint4*)((char*)Dl_ + lb) = *(const uint4*)(sl + (size_t)obl*64 + ku*8);
    }
    // twiddle A: rows 0..31 = Gr(r), 32..63 = Gi(r); k<32 acts on Yr, k>=32 on Yi; x(1/32)
    int l6 = t & 63, lo15 = l6 & 15, khi = l6 >> 4;
    bf16x8 Ath[8], Atl[8];
#pragma unroll
    for (int mt = 0; mt < 4; mt++) {
#pragma unroll
        for (int kst = 0; kst < 2; kst++) {
            int rrow = mt*16 + lo15;
            int rr = rrow & 31; bool gre = rrow < 32;
            unsigned short hh[8], ll[8];
#pragma unroll
            for (int e = 0; e < 8; e++) {
                int k = kst*32 + khi*8 + e;
                int ii = k & 31; bool kre = k < 32;
                float ang = TWO_PI_32 * (float)((rr * ii) & 31);
                float cv = cosf(ang), sv = sinf(ang);
                float v = gre ? (kre ? cv : -sv) : (kre ? sv : cv);
                v *= (1.f/32.f);
                hh[e] = f2bf(v); ll[e] = f2bf(v - bf2f(hh[e]));
            }
            uint4 uh = pk8(hh), ul = pk8(ll);
            Ath[mt*2+kst] = __builtin_bit_cast(bf16x8, uh);
            Atl[mt*2+kst] = __builtin_bit_cast(bf16x8, ul);
        }
    }
    __syncthreads();
    int w = t >> 6;
#pragma unroll
    for (int q = 0; q < 2; q++) {
        int nt = w*2 + q;
        int obl = nt*16 + lo15;
        bf16x8 Dh[2], Dl[2];
#pragma unroll
        for (int kst = 0; kst < 2; kst++) {
            int kb = (kst*32 + khi*8)*2;
            int ab = obl*128 + (kb ^ ((obl&7)<<4));
            Dh[kst] = *(bf16x8*)((char*)Dh_ + ab);
            Dl[kst] = *(bf16x8*)((char*)Dl_ + ab);
        }
#pragma unroll
        for (int mt = 0; mt < 4; mt++) {
            f32x4 acc = {0.f,0.f,0.f,0.f};
#pragma unroll
            for (int kst = 0; kst < 2; kst++) {
                acc = __builtin_amdgcn_mfma_f32_16x16x32_bf16(Ath[mt*2+kst], Dh[kst], acc, 0,0,0);
                acc = __builtin_amdgcn_mfma_f32_16x16x32_bf16(Atl[mt*2+kst], Dh[kst], acc, 0,0,0);
                acc = __builtin_amdgcn_mfma_f32_16x16x32_bf16(Ath[mt*2+kst], Dl[kst], acc, 0,0,0);
            }
            int rt = mt*16 + khi*4;
            int ob = obt*128 + nt*16 + lo15;
            float* gp = (rt < 32) ? Gr : Gi;
            int r0 = rt & 31;
            size_t di = ((size_t)j*8192 + ob)*32 + r0;
            *(float4*)(gp + di) = make_float4(acc[0], acc[1], acc[2], acc[3]);
        }
    }
}

// ---------------- final irfft along j + bias -> out[b][o][r][s] ----------------
__global__ __launch_bounds__(256) void irfft_j(const float* __restrict__ Gr,
                                               const float* __restrict__ Gi,
                                               const float* __restrict__ bias,
                                               float* __restrict__ out) {
    int gid = blockIdx.x * 256 + threadIdx.x;
    int ob = gid >> 5, r = gid & 31;
    int o = ob >> 5, b = ob & 31;
    __shared__ float2 wt[32];   // e^{+i 2pi m/32}
    if (threadIdx.x < 32) {
        float ph = 2.f * PI_F * (float)threadIdx.x / 32.f;
        wt[threadIdx.x] = make_float2(cosf(ph), sinf(ph));
    }
    __syncthreads();
    float2 Gv[17];
#pragma unroll
    for (int jj = 0; jj < 17; jj++) {
        size_t gi_ = ((size_t)jj * 8192 + ob) * 32 + r;
        Gv[jj] = make_float2(Gr[gi_], Gi[gi_]);
    }
    float y[32];
    float g0 = Gv[0].x, g16 = Gv[16].x;
#pragma unroll
    for (int s = 0; s < 32; s++) y[s] = g0 + ((s & 1) ? -g16 : g16);
#pragma unroll
    for (int jj = 1; jj < 16; jj++) {
        int js = 0;
#pragma unroll
        for (int s = 0; s < 32; s++) {
            float2 e = wt[js];
            y[s] += 2.f * (Gv[jj].x * e.x - Gv[jj].y * e.y);
            js = (js + jj) & 31;
        }
    }
    float bv = bias[o];
    float* op = out + ((size_t)(b * NCH + o) * 32 + r) * 32;
#pragma unroll
    for (int s = 0; s < 32; s++) op[s] = y[s] * (1.f/32.f) + bv;
}

extern "C" void kernel_launch(void* const* d_in, const int* in_sizes, int n_in,
                              void* d_out, int out_size, void* d_ws, size_t ws_size,
                              hipStream_t stream) {
    (void)in_sizes; (void)n_in; (void)out_size;
    if (ws_size < WS_NEED) return;

    const float* x     = (const float*)d_in[0];
    const float* w     = (const float*)d_in[1];
    const float* alpha = (const float*)d_in[2];
    const float* H     = (const float*)d_in[3];
    const float* bias  = (const float*)d_in[4];
    float* out = (float*)d_out;

    char* ws = (char*)d_ws;
    unsigned short* Afrag = (unsigned short*)(ws + OFF_AFRAG);
    unsigned short* Th    = (unsigned short*)(ws + OFF_TH);    // later Yh
    unsigned short* Tl    = (unsigned short*)(ws + OFF_TL);    // later Yl
    float* z32r = (float*)(ws + OFF_Z32R);                     // later Gr
    float* z32i = (float*)(ws + OFF_Z32I);                     // later Gi
    unsigned short* zbr   = (unsigned short*)(ws + OFF_ZBR);   // also wx real
    unsigned short* zbi   = (unsigned short*)(ws + OFF_ZBI);
    unsigned short* tbr   = (unsigned short*)(ws + OFF_TBR);
    unsigned short* tbi   = (unsigned short*)(ws + OFF_TBI);
    float2* wxh = (float2*)(ws + OFF_WXH);
    unsigned short* Hfrag = (unsigned short*)(ws + OFF_HFRAG);
    float* red = (float*)(ws + OFF_RED);
    float* sig = red + 256;

    norm_part<<<256, 256, 0, stream>>>(w, red);
    norm_final<<<1, 256, 0, stream>>>(red, alpha, sig);
    hfrag_build<<<dim3(8, 16), 64, 0, stream>>>(H, Hfrag);

    fft1_mfma<<<1024, 256, 0, stream>>>(x, Th, Tl);
    fft2_mfma<<<dim3(64, 17), 256, 0, stream>>>(Th, Tl, z32r, z32i, zbr, zbi);

    for (int ch = 0; ch < 2; ch++) {
        int f0 = ch * FPC;
        a_build_frag<<<dim3(16, 8, 4), 256, 0, stream>>>(w, sig, Afrag, f0);
        neum_pass<1><<<FPC*2, 256, 0, stream>>>(Afrag, zbr, zbi, z32r, z32i, tbr, tbi, f0);
        neum_pass<2><<<FPC*2, 256, 0, stream>>>(Afrag, tbr, tbi, z32r, z32i, zbr, zbi, f0);
        pass_h<<<FPC*2, 256, 0, stream>>>(Hfrag, zbr, zbi, wxh, f0);
    }

    // Yst aliases Th/Tl (dead after fft2); Gr/Gi alias z32 (dead after last neum)
    transpose_y<<<dim3(64, 17), 256, 0, stream>>>(wxh, Th, Tl);
    ifft_i_mfma<<<dim3(64, 17), 256, 0, stream>>>(Th, Tl, z32r, z32i);
    irfft_j<<<1024, 256, 0, stream>>>(z32r, z32i, bias, out);
}

// Round 5
// 360.029 us; speedup vs baseline: 1.7390x; 1.7390x over previous
//
#include <hip/hip_runtime.h>
#include <cstddef>

#define PI_F 3.14159265358979323846f

#define NCH 256   // C
#define NB  32    // B
#define NF  544   // n*(n/2+1),  f = i*17 + j
#define FPC 272   // freqs per A-chunk (2 chunks)

typedef short  bf16x8 __attribute__((ext_vector_type(8)));
typedef float  f32x4  __attribute__((ext_vector_type(4)));

// ---- workspace layout (bytes) ----
#define SZ_AFRAG ((size_t)FPC*8*16*2*1024)      // 71,303,168  (A fragments; G aliases here later)
#define SZ_PLANE ((size_t)NF*NB*NCH*2)          // 8,912,896   (bf16 plane [f][b][c])
#define SZ_P32   ((size_t)NF*NB*NCH*4)          // 17,825,792  (fp32 plane)
#define SZ_WXH   ((size_t)NF*8192*8)            // 35,651,584  (float2 [f][o*32+b]; also tmp)
#define OFF_AFRAG ((size_t)0)
#define OFF_ZBR  (OFF_AFRAG + SZ_AFRAG)         // z bf16 real; later wx real
#define OFF_ZBI  (OFF_ZBR + SZ_PLANE)
#define OFF_TBR  (OFF_ZBI + SZ_PLANE)
#define OFF_TBI  (OFF_TBR + SZ_PLANE)
#define OFF_Z32R (OFF_TBI + SZ_PLANE)
#define OFF_Z32I (OFF_Z32R + SZ_P32)
#define OFF_WXH  (OFF_Z32I + SZ_P32)            // wxh float2; also tmp (rfft2 out)
#define OFF_HFRAG (OFF_WXH + SZ_WXH)
#define SZ_HFRAG ((size_t)8*16*1024)            // 131,072
#define OFF_RED  (OFF_HFRAG + SZ_HFRAG)
#define WS_NEED  (OFF_RED + (size_t)4096)       // ~178.4 MB (proven available)

__device__ __forceinline__ unsigned short f2bf(float x) {
    unsigned int u = __float_as_uint(x);
    u += 0x7FFFu + ((u >> 16) & 1u);            // RNE
    return (unsigned short)(u >> 16);
}
__device__ __forceinline__ unsigned int pack2(float a, float b) {
    return (unsigned int)f2bf(a) | ((unsigned int)f2bf(b) << 16);
}

// ---------------- norm of wfft (closed form via Parseval) ----------------
__global__ void norm_part(const float* __restrict__ w, float* __restrict__ red) {
    int idx = blockIdx.x * 256 + threadIdx.x;
    const float* wp = w + (size_t)idx * 9;
    float s2 = 0.f, aa = 0.f, bb = 0.f;
#pragma unroll
    for (int u = 0; u < 3; u++) {
        float w0 = wp[u*3+0], w1 = wp[u*3+1], w2 = wp[u*3+2];
        s2 += w0*w0 + w1*w1 + w2*w2;
        float au = w0 + w1 + w2, bu = w0 - w1 + w2;
        aa += au*au; bb += bu*bu;
    }
    float p = 512.f*s2 + 16.f*(aa + bb);
    __shared__ float sm[256];
    sm[threadIdx.x] = p; __syncthreads();
    for (int s = 128; s > 0; s >>= 1) {
        if (threadIdx.x < s) sm[threadIdx.x] += sm[threadIdx.x + s];
        __syncthreads();
    }
    if (threadIdx.x == 0) red[blockIdx.x] = sm[0];
}

__global__ void norm_final(const float* __restrict__ red, const float* __restrict__ alpha,
                           float* __restrict__ sig) {
    __shared__ float sm[256];
    sm[threadIdx.x] = red[threadIdx.x]; __syncthreads();
    for (int s = 128; s > 0; s >>= 1) {
        if (threadIdx.x < s) sm[threadIdx.x] += sm[threadIdx.x + s];
        __syncthreads();
    }
    if (threadIdx.x == 0) sig[0] = alpha[0] / sqrtf(sm[0]);
}

// ---------------- H fragments (A-operand: m=o, k=c) ----------------
__global__ void hfrag_build(const float* __restrict__ H, unsigned short* __restrict__ Hfrag) {
    int kk = blockIdx.x, mt = blockIdx.y, lane = threadIdx.x;   // 64 threads
    int o = mt*16 + (lane & 15), c0 = kk*32 + (lane >> 4)*8;
    const float* hp = H + (size_t)o*NCH + c0;
    uint4 u;
    u.x = pack2(hp[0], hp[1]); u.y = pack2(hp[2], hp[3]);
    u.z = pack2(hp[4], hp[5]); u.w = pack2(hp[6], hp[7]);
    ((uint4*)Hfrag)[((size_t)kk*16 + mt)*64 + lane] = u;
}

// ---------------- rfft2 per (c,b) tile -> tmp[cb][f] ----------------
// bank-conflict fixes vs R2: separate wc/wsn float tables (float2 wtab aliased
// banks t/t+16 under lane-divergent indices -> 4-way); xt padded to stride 33.
__global__ void rfft2_tile(const float* __restrict__ x, float2* __restrict__ tmp) {
    int c = blockIdx.x >> 5, b = blockIdx.x & 31;
    __shared__ float  xt[1056];        // [r][s] stride 33
    __shared__ float2 T[544];          // [r*17+j]
    __shared__ float  wc[32], wsn[32];
    int t = threadIdx.x;
    const float* xp = x + ((size_t)(b * NCH + c)) * 1024;
    for (int m = t; m < 1024; m += 64) xt[(m >> 5) * 33 + (m & 31)] = xp[m];
    if (t < 32) {
        float ph = 2.f * PI_F * (float)t / 32.f;
        wc[t] = cosf(ph); wsn[t] = sinf(ph);
    }
    __syncthreads();
    // step 1: T[r][j] = sum_s x[r,s] * e^{-2pi i j s/32}
    for (int o = t; o < 544; o += 64) {
        int r = o / 17, j = o - r * 17;
        float ax = 0.f, ay = 0.f;
        for (int s = 0; s < 32; s++) {
            float xv = xt[r*33 + s];
            int m = (j * s) & 31;
            ax += xv * wc[m];
            ay -= xv * wsn[m];
        }
        T[o] = make_float2(ax, ay);
    }
    __syncthreads();
    // step 2: z[(i,j)] = sum_r e^{-2pi i i r/32} * T[r][j]
    float2* op = tmp + (size_t)blockIdx.x * 544;
    for (int o = t; o < 544; o += 64) {
        int i = o / 17, j = o - i * 17;
        float ax = 0.f, ay = 0.f;
        for (int r = 0; r < 32; r++) {
            int m = (i * r) & 31;
            float cc = wc[m], ss = wsn[m];
            float2 tv = T[r*17 + j];
            ax += cc*tv.x + ss*tv.y;
            ay += cc*tv.y - ss*tv.x;
        }
        op[o] = make_float2(ax, ay);
    }
}

// ---------------- transpose tmp[cb][f] -> plane layouts [f][b][c] (fp32 + bf16) ----------------
__global__ __launch_bounds__(256) void transpose_z(const float2* __restrict__ tmp,
        float* __restrict__ z32r, float* __restrict__ z32i,
        unsigned short* __restrict__ zbr, unsigned short* __restrict__ zbi)
{
    __shared__ float2 tile[32][33];
    int ct = blockIdx.x, ft = blockIdx.y, b = blockIdx.z;
    int t = threadIdx.x;
#pragma unroll
    for (int it = 0; it < 4; it++) {
        int idx = t + it*256; int cl = idx >> 5, fl = idx & 31;
        tile[cl][fl] = tmp[((size_t)((ct*32 + cl)*32 + b))*544 + ft*32 + fl];
    }
    __syncthreads();
#pragma unroll
    for (int it = 0; it < 4; it++) {
        int idx = t + it*256; int fl = idx >> 5, cl = idx & 31;
        float2 v = tile[cl][fl];
        size_t zi_ = ((size_t)(ft*32 + fl)*NB + b)*NCH + ct*32 + cl;
        z32r[zi_] = v.x; z32i[zi_] = v.y;
        zbr[zi_] = f2bf(v.x); zbi[zi_] = f2bf(v.y);
    }
}

// ---------------- A-build into MFMA fragment order (table-lookup form) ----------------
// A[c,cp] = sigma * sum_q [ (w1-w2)_q * Re(P_q) + i (w1+w2)_q * Im(P_q) ],
// P_q = e^{-2pi i (i(1-u)+j(1-v))/32}
__global__ __launch_bounds__(256) void a_build_frag(const float* __restrict__ w,
        const float* __restrict__ sig, unsigned short* __restrict__ Afrag, int f0)
{
    __shared__ float2 wtab[32];
    __shared__ unsigned short lar[512], lai[512];
    int t = threadIdx.x;
    if (t < 32) {
        float ph = -2.f * PI_F * (float)t / 32.f;
        wtab[t] = make_float2(cosf(ph), sinf(ph));
    }
    int mt = blockIdx.x, kk = blockIdx.y, fs = blockIdx.z;
    int c = mt*16 + (t & 15), cpl = t >> 4;
    int cpA = kk*32 + cpl, cpB = cpA + 16;
    float ua[9], va[9], ub[9], vb[9];
    {
        const float* pa1 = w + ((size_t)c*NCH + cpA)*9;
        const float* pb1 = w + ((size_t)c*NCH + cpB)*9;
        const float* pa2 = w + ((size_t)cpA*NCH + c)*9;
        const float* pb2 = w + ((size_t)cpB*NCH + c)*9;
#pragma unroll
        for (int q = 0; q < 9; q++) {
            float w1a = pa1[q], w2a = pa2[q], w1b = pb1[q], w2b = pb2[q];
            ua[q] = w1a - w2a; va[q] = w1a + w2a;
            ub[q] = w1b - w2b; vb[q] = w1b + w2b;
        }
    }
    float s = sig[0];
    int la_ = ((c & 15) + 16*(cpl>>3))*8 + (cpl & 7);
    int lb_ = la_ + 32*8;
    __syncthreads();
    for (int fl = fs*68; fl < fs*68 + 68; fl++) {
        int f = f0 + fl;
        int i = f / 17, jj = f - i * 17;    // f = i*17 + j ordering (matches rfft2/transpose)
        int m_[9];
        m_[0] = (i + jj) & 31;  m_[1] = i;             m_[2] = (i - jj) & 31;
        m_[3] = jj;             m_[4] = 0;             m_[5] = (32 - jj) & 31;
        m_[6] = (jj - i) & 31;  m_[7] = (32 - i) & 31; m_[8] = (64 - i - jj) & 31;
        float ArA = 0.f, AiA = 0.f, ArB = 0.f, AiB = 0.f;
#pragma unroll
        for (int q = 0; q < 9; q++) {
            float2 P = wtab[m_[q]];
            ArA += ua[q] * P.x; AiA += va[q] * P.y;
            ArB += ub[q] * P.x; AiB += vb[q] * P.y;
        }
        lar[la_] = f2bf(s*ArA); lai[la_] = f2bf(s*AiA);
        lar[lb_] = f2bf(s*ArB); lai[lb_] = f2bf(s*AiB);
        __syncthreads();
        size_t bch = (((size_t)fl*8 + kk)*16 + mt)*256;   // uint2 units
        ((uint2*)Afrag)[bch + t] = (t < 128) ? ((const uint2*)lar)[t]
                                             : ((const uint2*)lai)[t - 128];
        __syncthreads();
    }
}

// ---------------- Neumann pass via MFMA ----------------
// MODE 1: out = z32 - acc   (t = z - A z)
// MODE 2: out = z32 - 2*acc (wx = z - 2 A t)
template<int MODE>
__global__ __launch_bounds__(256) void neum_pass(
    const unsigned short* __restrict__ Afrag,
    const unsigned short* __restrict__ BR, const unsigned short* __restrict__ BI,
    const float* __restrict__ z32r, const float* __restrict__ z32i,
    unsigned short* __restrict__ outR, unsigned short* __restrict__ outI, int f0)
{
    __shared__ uint4 lz[2][1024];   // 32 KB, swizzled
    int fl = blockIdx.x >> 1, half = blockIdx.x & 1;
    int f = f0 + fl;
    int t = threadIdx.x;
    const uint4* s0 = (const uint4*)(BR + (size_t)f*8192);
    const uint4* s1 = (const uint4*)(BI + (size_t)f*8192);
    for (int u = t; u < 1024; u += 256) {
        int b = u >> 5, o16 = u & 31;
        int du = b*32 + (o16 ^ (b & 7));
        lz[0][du] = s0[u];
        lz[1][du] = s1[u];
    }
    __syncthreads();
    int w = t >> 6, lane = t & 63, lo = lane & 15, hi = lane >> 4;
    f32x4 accr[2][2], acci[2][2];
    f32x4 zz = {0.f, 0.f, 0.f, 0.f};
#pragma unroll
    for (int mt = 0; mt < 2; mt++)
#pragma unroll
        for (int nt = 0; nt < 2; nt++) { accr[mt][nt] = zz; acci[mt][nt] = zz; }
    const uint4* A4 = (const uint4*)Afrag;
    for (int kk = 0; kk < 8; kk++) {
        bf16x8 ar[2], ai[2], ain[2];
#pragma unroll
        for (int mt = 0; mt < 2; mt++) {
            int mtg = half*8 + w*2 + mt;
            size_t idx = ((((size_t)fl*8 + kk)*16 + mtg)*2)*64 + lane;
            uint4 va = A4[idx], vb = A4[idx + 64];
            ar[mt] = __builtin_bit_cast(bf16x8, va);
            ai[mt] = __builtin_bit_cast(bf16x8, vb);
            uint4 vn = make_uint4(vb.x ^ 0x80008000u, vb.y ^ 0x80008000u,
                                  vb.z ^ 0x80008000u, vb.w ^ 0x80008000u);
            ain[mt] = __builtin_bit_cast(bf16x8, vn);
        }
        bf16x8 zr[2], zi_[2];
#pragma unroll
        for (int nt = 0; nt < 2; nt++) {
            int b = nt*16 + lo;
            int du = b*32 + ((kk*4 + hi) ^ (b & 7));
            zr[nt]  = __builtin_bit_cast(bf16x8, lz[0][du]);
            zi_[nt] = __builtin_bit_cast(bf16x8, lz[1][du]);
        }
#pragma unroll
        for (int mt = 0; mt < 2; mt++)
#pragma unroll
            for (int nt = 0; nt < 2; nt++) {
                accr[mt][nt] = __builtin_amdgcn_mfma_f32_16x16x32_bf16(ar[mt],  zr[nt],  accr[mt][nt], 0, 0, 0);
                accr[mt][nt] = __builtin_amdgcn_mfma_f32_16x16x32_bf16(ain[mt], zi_[nt], accr[mt][nt], 0, 0, 0);
                acci[mt][nt] = __builtin_amdgcn_mfma_f32_16x16x32_bf16(ar[mt],  zi_[nt], acci[mt][nt], 0, 0, 0);
                acci[mt][nt] = __builtin_amdgcn_mfma_f32_16x16x32_bf16(ai[mt],  zr[nt],  acci[mt][nt], 0, 0, 0);
            }
    }
#pragma unroll
    for (int mt = 0; mt < 2; mt++)
#pragma unroll
        for (int nt = 0; nt < 2; nt++) {
            int c0 = half*128 + w*32 + mt*16 + hi*4;
            int b  = nt*16 + lo;
            size_t zb = ((size_t)f*NB + b)*NCH + c0;
            float vr[4], vi[4];
#pragma unroll
            for (int jj = 0; jj < 4; jj++) {
                float zrv = z32r[zb + jj], ziv = z32i[zb + jj];
                float cr = accr[mt][nt][jj], ci = acci[mt][nt][jj];
                if (MODE == 1) { vr[jj] = zrv - cr;      vi[jj] = ziv - ci; }
                else           { vr[jj] = zrv - 2.f*cr;  vi[jj] = ziv - 2.f*ci; }
            }
            *(uint2*)(outR + zb) = make_uint2(pack2(vr[0], vr[1]), pack2(vr[2], vr[3]));
            *(uint2*)(outI + zb) = make_uint2(pack2(vi[0], vi[1]), pack2(vi[2], vi[3]));
        }
}

// ---------------- H pass via MFMA: wxh[f][o*32+b] = sum_c H[o,c] wx[f,c,b] ----------------
__global__ __launch_bounds__(256) void pass_h(
    const unsigned short* __restrict__ Hfrag,
    const unsigned short* __restrict__ BR, const unsigned short* __restrict__ BI,
    float2* __restrict__ wxh, int f0)
{
    __shared__ uint4 lz[2][1024];
    int fl = blockIdx.x >> 1, half = blockIdx.x & 1;
    int f = f0 + fl;
    int t = threadIdx.x;
    const uint4* s0 = (const uint4*)(BR + (size_t)f*8192);
    const uint4* s1 = (const uint4*)(BI + (size_t)f*8192);
    for (int u = t; u < 1024; u += 256) {
        int b = u >> 5, o16 = u & 31;
        int du = b*32 + (o16 ^ (b & 7));
        lz[0][du] = s0[u];
        lz[1][du] = s1[u];
    }
    __syncthreads();
    int w = t >> 6, lane = t & 63, lo = lane & 15, hi = lane >> 4;
    f32x4 accr[2][2], acci[2][2];
    f32x4 zz = {0.f, 0.f, 0.f, 0.f};
#pragma unroll
    for (int mt = 0; mt < 2; mt++)
#pragma unroll
        for (int nt = 0; nt < 2; nt++) { accr[mt][nt] = zz; acci[mt][nt] = zz; }
    const uint4* H4 = (const uint4*)Hfrag;
    for (int kk = 0; kk < 8; kk++) {
        bf16x8 hm[2];
#pragma unroll
        for (int mt = 0; mt < 2; mt++) {
            int mtg = half*8 + w*2 + mt;
            hm[mt] = __builtin_bit_cast(bf16x8, H4[((size_t)kk*16 + mtg)*64 + lane]);
        }
        bf16x8 zr[2], zi_[2];
#pragma unroll
        for (int nt = 0; nt < 2; nt++) {
            int b = nt*16 + lo;
            int du = b*32 + ((kk*4 + hi) ^ (b & 7));
            zr[nt]  = __builtin_bit_cast(bf16x8, lz[0][du]);
            zi_[nt] = __builtin_bit_cast(bf16x8, lz[1][du]);
        }
#pragma unroll
        for (int mt = 0; mt < 2; mt++)
#pragma unroll
            for (int nt = 0; nt < 2; nt++) {
                accr[mt][nt] = __builtin_amdgcn_mfma_f32_16x16x32_bf16(hm[mt], zr[nt],  accr[mt][nt], 0, 0, 0);
                acci[mt][nt] = __builtin_amdgcn_mfma_f32_16x16x32_bf16(hm[mt], zi_[nt], acci[mt][nt], 0, 0, 0);
            }
    }
#pragma unroll
    for (int mt = 0; mt < 2; mt++)
#pragma unroll
        for (int nt = 0; nt < 2; nt++) {
            int o0 = half*128 + w*32 + mt*16 + hi*4;
            int b  = nt*16 + lo;
#pragma unroll
            for (int jj = 0; jj < 4; jj++) {
                wxh[((size_t)f*NCH + o0 + jj)*NB + b] =
                    make_float2(accr[mt][nt][jj], acci[mt][nt][jj]);
            }
        }
}

// ---------------- pass I: complex ifft along i: G[j][ob][r] ----------------
__global__ __launch_bounds__(256) void ifft_i(const float2* __restrict__ wxh, float2* __restrict__ G) {
    int j = blockIdx.x >> 5, obc = blockIdx.x & 31;
    int ob = obc * 256 + threadIdx.x;
    __shared__ float2 wt[32];   // e^{+i 2pi m/32} (reads are wave-uniform -> broadcast, no conflict)
    if (threadIdx.x < 32) {
        float ph = 2.f * PI_F * (float)threadIdx.x / 32.f;
        wt[threadIdx.x] = make_float2(cosf(ph), sinf(ph));
    }
    __syncthreads();
    float2 Gacc[32];
#pragma unroll
    for (int r = 0; r < 32; r++) Gacc[r] = make_float2(0.f, 0.f);
    for (int i = 0; i < 32; i++) {
        float2 Y = wxh[((size_t)(i * 17 + j)) * 8192 + ob];
        int ir = 0;
#pragma unroll
        for (int r = 0; r < 32; r++) {
            float2 e = wt[ir];
            Gacc[r].x += Y.x*e.x - Y.y*e.y;
            Gacc[r].y += Y.x*e.y + Y.y*e.x;
            ir = (ir + i) & 31;
        }
    }
    float2* gp = G + ((size_t)j * 8192 + ob) * 32;
#pragma unroll
    for (int r = 0; r < 32; r++)
        gp[r] = make_float2(Gacc[r].x * (1.f/32.f), Gacc[r].y * (1.f/32.f));
}

// ---------------- pass II: irfft along j + bias -> out[b][o][r][s] ----------------
__global__ __launch_bounds__(256) void irfft_j(const float2* __restrict__ G,
                                               const float* __restrict__ bias,
                                               float* __restrict__ out) {
    int gid = blockIdx.x * 256 + threadIdx.x;
    int ob = gid >> 5, r = gid & 31;
    int o = ob >> 5, b = ob & 31;
    __shared__ float2 wt[32];
    if (threadIdx.x < 32) {
        float ph = 2.f * PI_F * (float)threadIdx.x / 32.f;
        wt[threadIdx.x] = make_float2(cosf(ph), sinf(ph));
    }
    __syncthreads();
    float2 Gv[17];
#pragma unroll
    for (int jj = 0; jj < 17; jj++) Gv[jj] = G[((size_t)jj * 8192 + ob) * 32 + r];
    float y[32];
    float g0 = Gv[0].x, g16 = Gv[16].x;
#pragma unroll
    for (int s = 0; s < 32; s++) y[s] = g0 + ((s & 1) ? -g16 : g16);
#pragma unroll
    for (int jj = 1; jj < 16; jj++) {
        int js = 0;
#pragma unroll
        for (int s = 0; s < 32; s++) {
            float2 e = wt[js];
            y[s] += 2.f * (Gv[jj].x * e.x - Gv[jj].y * e.y);
            js = (js + jj) & 31;
        }
    }
    float bv = bias[o];
    float* op = out + ((size_t)(b * NCH + o) * 32 + r) * 32;
#pragma unroll
    for (int s = 0; s < 32; s++) op[s] = y[s] * (1.f/32.f) + bv;
}

extern "C" void kernel_launch(void* const* d_in, const int* in_sizes, int n_in,
                              void* d_out, int out_size, void* d_ws, size_t ws_size,
                              hipStream_t stream) {
    (void)in_sizes; (void)n_in; (void)out_size;
    if (ws_size < WS_NEED) return;

    const float* x     = (const float*)d_in[0];
    const float* w     = (const float*)d_in[1];
    const float* alpha = (const float*)d_in[2];
    const float* H     = (const float*)d_in[3];
    const float* bias  = (const float*)d_in[4];
    float* out = (float*)d_out;

    char* ws = (char*)d_ws;
    unsigned short* Afrag = (unsigned short*)(ws + OFF_AFRAG);
    unsigned short* zbr   = (unsigned short*)(ws + OFF_ZBR);   // also wx real
    unsigned short* zbi   = (unsigned short*)(ws + OFF_ZBI);
    unsigned short* tbr   = (unsigned short*)(ws + OFF_TBR);
    unsigned short* tbi   = (unsigned short*)(ws + OFF_TBI);
    float* z32r = (float*)(ws + OFF_Z32R);
    float* z32i = (float*)(ws + OFF_Z32I);
    float2* wxh = (float2*)(ws + OFF_WXH);   // aliases tmp
    float2* tmp = (float2*)(ws + OFF_WXH);
    float2* G   = (float2*)(ws + OFF_AFRAG); // aliases Afrag (dead after passes)
    unsigned short* Hfrag = (unsigned short*)(ws + OFF_HFRAG);
    float* red = (float*)(ws + OFF_RED);
    float* sig = red + 256;

    norm_part<<<256, 256, 0, stream>>>(w, red);
    norm_final<<<1, 256, 0, stream>>>(red, alpha, sig);
    hfrag_build<<<dim3(8, 16), 64, 0, stream>>>(H, Hfrag);

    rfft2_tile<<<8192, 64, 0, stream>>>(x, tmp);
    transpose_z<<<dim3(8, 17, 32), 256, 0, stream>>>(tmp, z32r, z32i, zbr, zbi);

    for (int ch = 0; ch < 2; ch++) {
        int f0 = ch * FPC;
        a_build_frag<<<dim3(16, 8, 4), 256, 0, stream>>>(w, sig, Afrag, f0);
        neum_pass<1><<<FPC*2, 256, 0, stream>>>(Afrag, zbr, zbi, z32r, z32i, tbr, tbi, f0);
        neum_pass<2><<<FPC*2, 256, 0, stream>>>(Afrag, tbr, tbi, z32r, z32i, zbr, zbi, f0);
        pass_h<<<FPC*2, 256, 0, stream>>>(Hfrag, zbr, zbi, wxh, f0);
    }

    ifft_i<<<544, 256, 0, stream>>>(wxh, G);
    irfft_j<<<1024, 256, 0, stream>>>(G, bias, out);
}

// Round 6
// 326.406 us; speedup vs baseline: 1.9182x; 1.1030x over previous
//
#include <hip/hip_runtime.h>
#include <cstddef>

#define PI_F 3.14159265358979323846f

#define NCH 256   // C
#define NB  32    // B
#define NF  544   // n*(n/2+1),  f = i*17 + j
#define FPC 272   // freqs per A-chunk (2 chunks)

typedef short  bf16x8 __attribute__((ext_vector_type(8)));
typedef float  f32x4  __attribute__((ext_vector_type(4)));

// ---- workspace layout (bytes) ----
#define SZ_AFRAG ((size_t)FPC*8*16*2*1024)      // 71,303,168  (A fragments; G aliases here later)
#define SZ_PLANE ((size_t)NF*NB*NCH*2)          // 8,912,896   (bf16 plane [f][b][c])
#define SZ_P32   ((size_t)NF*NB*NCH*4)          // 17,825,792  (fp32 plane)
#define SZ_WXH   ((size_t)NF*8192*8)            // 35,651,584  (float2 [f][o*32+b]; also tmp)
#define OFF_AFRAG ((size_t)0)
#define OFF_ZBR  (OFF_AFRAG + SZ_AFRAG)         // z bf16 real; later wx real
#define OFF_ZBI  (OFF_ZBR + SZ_PLANE)
#define OFF_TBR  (OFF_ZBI + SZ_PLANE)
#define OFF_TBI  (OFF_TBR + SZ_PLANE)
#define OFF_Z32R (OFF_TBI + SZ_PLANE)
#define OFF_Z32I (OFF_Z32R + SZ_P32)
#define OFF_WXH  (OFF_Z32I + SZ_P32)            // wxh float2; also tmp (rfft2 out)
#define OFF_HFRAG (OFF_WXH + SZ_WXH)
#define SZ_HFRAG ((size_t)8*16*1024)            // 131,072
#define OFF_RED  (OFF_HFRAG + SZ_HFRAG)
#define WS_NEED  (OFF_RED + (size_t)4096)       // ~178.4 MB (proven available)

// 32-point twiddle tables, positive phase: COS32[k]=cos(2pi k/32), SIN32[k]=sin(2pi k/32)
__device__ constexpr float COS32[32] = {
     1.0000000000f,  0.9807852804f,  0.9238795325f,  0.8314696123f,
     0.7071067812f,  0.5555702330f,  0.3826834324f,  0.1950903220f,
     0.0000000000f, -0.1950903220f, -0.3826834324f, -0.5555702330f,
    -0.7071067812f, -0.8314696123f, -0.9238795325f, -0.9807852804f,
    -1.0000000000f, -0.9807852804f, -0.9238795325f, -0.8314696123f,
    -0.7071067812f, -0.5555702330f, -0.3826834324f, -0.1950903220f,
    -0.0000000000f,  0.1950903220f,  0.3826834324f,  0.5555702330f,
     0.7071067812f,  0.8314696123f,  0.9238795325f,  0.9807852804f };
__device__ constexpr float SIN32[32] = {
     0.0000000000f,  0.1950903220f,  0.3826834324f,  0.5555702330f,
     0.7071067812f,  0.8314696123f,  0.9238795325f,  0.9807852804f,
     1.0000000000f,  0.9807852804f,  0.9238795325f,  0.8314696123f,
     0.7071067812f,  0.5555702330f,  0.3826834324f,  0.1950903220f,
     0.0000000000f, -0.1950903220f, -0.3826834324f, -0.5555702330f,
    -0.7071067812f, -0.8314696123f, -0.9238795325f, -0.9807852804f,
    -1.0000000000f, -0.9807852804f, -0.9238795325f, -0.8314696123f,
    -0.7071067812f, -0.5555702330f, -0.3826834324f, -0.1950903220f };

__device__ __forceinline__ unsigned short f2bf(float x) {
    unsigned int u = __float_as_uint(x);
    u += 0x7FFFu + ((u >> 16) & 1u);            // RNE
    return (unsigned short)(u >> 16);
}
__device__ __forceinline__ unsigned int pack2(float a, float b) {
    return (unsigned int)f2bf(a) | ((unsigned int)f2bf(b) << 16);
}

// ---------------- norm of wfft (closed form via Parseval) ----------------
__global__ void norm_part(const float* __restrict__ w, float* __restrict__ red) {
    int idx = blockIdx.x * 256 + threadIdx.x;
    const float* wp = w + (size_t)idx * 9;
    float s2 = 0.f, aa = 0.f, bb = 0.f;
#pragma unroll
    for (int u = 0; u < 3; u++) {
        float w0 = wp[u*3+0], w1 = wp[u*3+1], w2 = wp[u*3+2];
        s2 += w0*w0 + w1*w1 + w2*w2;
        float au = w0 + w1 + w2, bu = w0 - w1 + w2;
        aa += au*au; bb += bu*bu;
    }
    float p = 512.f*s2 + 16.f*(aa + bb);
    __shared__ float sm[256];
    sm[threadIdx.x] = p; __syncthreads();
    for (int s = 128; s > 0; s >>= 1) {
        if (threadIdx.x < s) sm[threadIdx.x] += sm[threadIdx.x + s];
        __syncthreads();
    }
    if (threadIdx.x == 0) red[blockIdx.x] = sm[0];
}

__global__ void norm_final(const float* __restrict__ red, const float* __restrict__ alpha,
                           float* __restrict__ sig) {
    __shared__ float sm[256];
    sm[threadIdx.x] = red[threadIdx.x]; __syncthreads();
    for (int s = 128; s > 0; s >>= 1) {
        if (threadIdx.x < s) sm[threadIdx.x] += sm[threadIdx.x + s];
        __syncthreads();
    }
    if (threadIdx.x == 0) sig[0] = alpha[0] / sqrtf(sm[0]);
}

// ---------------- H fragments (A-operand: m=o, k=c) ----------------
__global__ void hfrag_build(const float* __restrict__ H, unsigned short* __restrict__ Hfrag) {
    int kk = blockIdx.x, mt = blockIdx.y, lane = threadIdx.x;   // 64 threads
    int o = mt*16 + (lane & 15), c0 = kk*32 + (lane >> 4)*8;
    const float* hp = H + (size_t)o*NCH + c0;
    uint4 u;
    u.x = pack2(hp[0], hp[1]); u.y = pack2(hp[2], hp[3]);
    u.z = pack2(hp[4], hp[5]); u.w = pack2(hp[6], hp[7]);
    ((uint4*)Hfrag)[((size_t)kk*16 + mt)*64 + lane] = u;
}

// ---------------- rfft2: register-resident DFT, 2 tiles per wave ----------------
// lanes 0-31 = tile A, 32-63 = tile B. Step 1 twiddles are compile-time
// literals (zero LDS); step 2 twiddles preloaded per-lane into VGPRs.
__global__ __launch_bounds__(64) void rfft2_reg(const float* __restrict__ x,
                                                float2* __restrict__ tmp)
{
    __shared__ float2 T[2][544];       // [half][r*17+j]
    __shared__ float wc[32], wsn[32];
    int t = threadIdx.x;
    int half = t >> 5, lane = t & 31;
    int cb = blockIdx.x * 2 + half;    // tile index in tmp order: cb = c*32 + b
    int c = cb >> 5, b = cb & 31;
    if (t < 32) { wc[t] = COS32[t]; wsn[t] = SIN32[t]; }
    // load row r=lane of this tile into registers
    float xr[32];
    const float* xp = x + ((size_t)(b * NCH + c)) * 1024 + lane * 32;
#pragma unroll
    for (int q = 0; q < 8; q++) {
        float4 v = *(const float4*)(xp + q*4);
        xr[q*4+0] = v.x; xr[q*4+1] = v.y; xr[q*4+2] = v.z; xr[q*4+3] = v.w;
    }
    // step 1: T[r=lane][j] = sum_s x[r,s] e^{-2pi i j s/32}   (constant twiddles)
#pragma unroll
    for (int j = 0; j < 17; j++) {
        float ax = 0.f, ay = 0.f;
#pragma unroll
        for (int s = 0; s < 32; s++) {
            constexpr int dummy = 0; (void)dummy;
            int m = (j * s) & 31;
            ax += xr[s] * COS32[m];
            ay -= xr[s] * SIN32[m];
        }
        T[half][lane*17 + j] = make_float2(ax, ay);
    }
    __syncthreads();
    // preload per-lane (i = lane) twiddles: w[(i*r)&31], conflict-free LDS reads
    float wr_[32], wi_[32];
#pragma unroll
    for (int r = 0; r < 32; r++) {
        int m = (lane * r) & 31;
        wr_[r] = wc[m]; wi_[r] = wsn[m];
    }
    // step 2: z[i=lane][j] = sum_r e^{-2pi i i r/32} T[r][j]  (T reads broadcast)
    float2* op = tmp + (size_t)cb * 544 + lane * 17;
#pragma unroll
    for (int j = 0; j < 17; j++) {
        float ax = 0.f, ay = 0.f;
#pragma unroll
        for (int r = 0; r < 32; r++) {
            float2 tv = T[half][r*17 + j];
            ax += tv.x * wr_[r] + tv.y * wi_[r];
            ay += tv.y * wr_[r] - tv.x * wi_[r];
        }
        op[j] = make_float2(ax, ay);
    }
}

// ---------------- transpose tmp[cb][f] -> plane layouts [f][b][c] (fp32 + bf16) ----------------
__global__ __launch_bounds__(256) void transpose_z(const float2* __restrict__ tmp,
        float* __restrict__ z32r, float* __restrict__ z32i,
        unsigned short* __restrict__ zbr, unsigned short* __restrict__ zbi)
{
    __shared__ float2 tile[32][33];
    int ct = blockIdx.x, ft = blockIdx.y, b = blockIdx.z;
    int t = threadIdx.x;
#pragma unroll
    for (int it = 0; it < 4; it++) {
        int idx = t + it*256; int cl = idx >> 5, fl = idx & 31;
        tile[cl][fl] = tmp[((size_t)((ct*32 + cl)*32 + b))*544 + ft*32 + fl];
    }
    __syncthreads();
#pragma unroll
    for (int it = 0; it < 4; it++) {
        int idx = t + it*256; int fl = idx >> 5, cl = idx & 31;
        float2 v = tile[cl][fl];
        size_t zi_ = ((size_t)(ft*32 + fl)*NB + b)*NCH + ct*32 + cl;
        z32r[zi_] = v.x; z32i[zi_] = v.y;
        zbr[zi_] = f2bf(v.x); zbi[zi_] = f2bf(v.y);
    }
}

// ---------------- A-build into MFMA fragment order (table-lookup form) ----------------
// A[c,cp] = sigma * sum_q [ (w1-w2)_q * Re(P_q) + i (w1+w2)_q * Im(P_q) ],
// P_q = e^{-2pi i (i(1-u)+j(1-v))/32}
__global__ __launch_bounds__(256) void a_build_frag(const float* __restrict__ w,
        const float* __restrict__ sig, unsigned short* __restrict__ Afrag, int f0)
{
    __shared__ float2 wtab[32];
    __shared__ unsigned short lar[512], lai[512];
    int t = threadIdx.x;
    if (t < 32) {
        float ph = -2.f * PI_F * (float)t / 32.f;
        wtab[t] = make_float2(cosf(ph), sinf(ph));
    }
    int mt = blockIdx.x, kk = blockIdx.y, fs = blockIdx.z;
    int c = mt*16 + (t & 15), cpl = t >> 4;
    int cpA = kk*32 + cpl, cpB = cpA + 16;
    float ua[9], va[9], ub[9], vb[9];
    {
        const float* pa1 = w + ((size_t)c*NCH + cpA)*9;
        const float* pb1 = w + ((size_t)c*NCH + cpB)*9;
        const float* pa2 = w + ((size_t)cpA*NCH + c)*9;
        const float* pb2 = w + ((size_t)cpB*NCH + c)*9;
#pragma unroll
        for (int q = 0; q < 9; q++) {
            float w1a = pa1[q], w2a = pa2[q], w1b = pb1[q], w2b = pb2[q];
            ua[q] = w1a - w2a; va[q] = w1a + w2a;
            ub[q] = w1b - w2b; vb[q] = w1b + w2b;
        }
    }
    float s = sig[0];
    int la_ = ((c & 15) + 16*(cpl>>3))*8 + (cpl & 7);
    int lb_ = la_ + 32*8;
    __syncthreads();
    for (int fl = fs*68; fl < fs*68 + 68; fl++) {
        int f = f0 + fl;
        int i = f / 17, jj = f - i * 17;    // f = i*17 + j ordering
        int m_[9];
        m_[0] = (i + jj) & 31;  m_[1] = i;             m_[2] = (i - jj) & 31;
        m_[3] = jj;             m_[4] = 0;             m_[5] = (32 - jj) & 31;
        m_[6] = (jj - i) & 31;  m_[7] = (32 - i) & 31; m_[8] = (64 - i - jj) & 31;
        float ArA = 0.f, AiA = 0.f, ArB = 0.f, AiB = 0.f;
#pragma unroll
        for (int q = 0; q < 9; q++) {
            float2 P = wtab[m_[q]];
            ArA += ua[q] * P.x; AiA += va[q] * P.y;
            ArB += ub[q] * P.x; AiB += vb[q] * P.y;
        }
        lar[la_] = f2bf(s*ArA); lai[la_] = f2bf(s*AiA);
        lar[lb_] = f2bf(s*ArB); lai[lb_] = f2bf(s*AiB);
        __syncthreads();
        size_t bch = (((size_t)fl*8 + kk)*16 + mt)*256;   // uint2 units
        ((uint2*)Afrag)[bch + t] = (t < 128) ? ((const uint2*)lar)[t]
                                             : ((const uint2*)lai)[t - 128];
        __syncthreads();
    }
}

// ---------------- Neumann pass via MFMA ----------------
// MODE 1: out = z32 - acc   (t = z - A z)
// MODE 2: out = z32 - 2*acc (wx = z - 2 A t)
template<int MODE>
__global__ __launch_bounds__(256) void neum_pass(
    const unsigned short* __restrict__ Afrag,
    const unsigned short* __restrict__ BR, const unsigned short* __restrict__ BI,
    const float* __restrict__ z32r, const float* __restrict__ z32i,
    unsigned short* __restrict__ outR, unsigned short* __restrict__ outI, int f0)
{
    __shared__ uint4 lz[2][1024];   // 32 KB, swizzled
    int fl = blockIdx.x >> 1, half = blockIdx.x & 1;
    int f = f0 + fl;
    int t = threadIdx.x;
    const uint4* s0 = (const uint4*)(BR + (size_t)f*8192);
    const uint4* s1 = (const uint4*)(BI + (size_t)f*8192);
    for (int u = t; u < 1024; u += 256) {
        int b = u >> 5, o16 = u & 31;
        int du = b*32 + (o16 ^ (b & 7));
        lz[0][du] = s0[u];
        lz[1][du] = s1[u];
    }
    __syncthreads();
    int w = t >> 6, lane = t & 63, lo = lane & 15, hi = lane >> 4;
    f32x4 accr[2][2], acci[2][2];
    f32x4 zz = {0.f, 0.f, 0.f, 0.f};
#pragma unroll
    for (int mt = 0; mt < 2; mt++)
#pragma unroll
        for (int nt = 0; nt < 2; nt++) { accr[mt][nt] = zz; acci[mt][nt] = zz; }
    const uint4* A4 = (const uint4*)Afrag;
    for (int kk = 0; kk < 8; kk++) {
        bf16x8 ar[2], ai[2], ain[2];
#pragma unroll
        for (int mt = 0; mt < 2; mt++) {
            int mtg = half*8 + w*2 + mt;
            size_t idx = ((((size_t)fl*8 + kk)*16 + mtg)*2)*64 + lane;
            uint4 va = A4[idx], vb = A4[idx + 64];
            ar[mt] = __builtin_bit_cast(bf16x8, va);
            ai[mt] = __builtin_bit_cast(bf16x8, vb);
            uint4 vn = make_uint4(vb.x ^ 0x80008000u, vb.y ^ 0x80008000u,
                                  vb.z ^ 0x80008000u, vb.w ^ 0x80008000u);
            ain[mt] = __builtin_bit_cast(bf16x8, vn);
        }
        bf16x8 zr[2], zi_[2];
#pragma unroll
        for (int nt = 0; nt < 2; nt++) {
            int b = nt*16 + lo;
            int du = b*32 + ((kk*4 + hi) ^ (b & 7));
            zr[nt]  = __builtin_bit_cast(bf16x8, lz[0][du]);
            zi_[nt] = __builtin_bit_cast(bf16x8, lz[1][du]);
        }
#pragma unroll
        for (int mt = 0; mt < 2; mt++)
#pragma unroll
            for (int nt = 0; nt < 2; nt++) {
                accr[mt][nt] = __builtin_amdgcn_mfma_f32_16x16x32_bf16(ar[mt],  zr[nt],  accr[mt][nt], 0, 0, 0);
                accr[mt][nt] = __builtin_amdgcn_mfma_f32_16x16x32_bf16(ain[mt], zi_[nt], accr[mt][nt], 0, 0, 0);
                acci[mt][nt] = __builtin_amdgcn_mfma_f32_16x16x32_bf16(ar[mt],  zi_[nt], acci[mt][nt], 0, 0, 0);
                acci[mt][nt] = __builtin_amdgcn_mfma_f32_16x16x32_bf16(ai[mt],  zr[nt],  acci[mt][nt], 0, 0, 0);
            }
    }
#pragma unroll
    for (int mt = 0; mt < 2; mt++)
#pragma unroll
        for (int nt = 0; nt < 2; nt++) {
            int c0 = half*128 + w*32 + mt*16 + hi*4;
            int b  = nt*16 + lo;
            size_t zb = ((size_t)f*NB + b)*NCH + c0;
            float vr[4], vi[4];
#pragma unroll
            for (int jj = 0; jj < 4; jj++) {
                float zrv = z32r[zb + jj], ziv = z32i[zb + jj];
                float cr = accr[mt][nt][jj], ci = acci[mt][nt][jj];
                if (MODE == 1) { vr[jj] = zrv - cr;      vi[jj] = ziv - ci; }
                else           { vr[jj] = zrv - 2.f*cr;  vi[jj] = ziv - 2.f*ci; }
            }
            *(uint2*)(outR + zb) = make_uint2(pack2(vr[0], vr[1]), pack2(vr[2], vr[3]));
            *(uint2*)(outI + zb) = make_uint2(pack2(vi[0], vi[1]), pack2(vi[2], vi[3]));
        }
}

// ---------------- H pass via MFMA: wxh[f][o*32+b] = sum_c H[o,c] wx[f,c,b] ----------------
__global__ __launch_bounds__(256) void pass_h(
    const unsigned short* __restrict__ Hfrag,
    const unsigned short* __restrict__ BR, const unsigned short* __restrict__ BI,
    float2* __restrict__ wxh, int f0)
{
    __shared__ uint4 lz[2][1024];
    int fl = blockIdx.x >> 1, half = blockIdx.x & 1;
    int f = f0 + fl;
    int t = threadIdx.x;
    const uint4* s0 = (const uint4*)(BR + (size_t)f*8192);
    const uint4* s1 = (const uint4*)(BI + (size_t)f*8192);
    for (int u = t; u < 1024; u += 256) {
        int b = u >> 5, o16 = u & 31;
        int du = b*32 + (o16 ^ (b & 7));
        lz[0][du] = s0[u];
        lz[1][du] = s1[u];
    }
    __syncthreads();
    int w = t >> 6, lane = t & 63, lo = lane & 15, hi = lane >> 4;
    f32x4 accr[2][2], acci[2][2];
    f32x4 zz = {0.f, 0.f, 0.f, 0.f};
#pragma unroll
    for (int mt = 0; mt < 2; mt++)
#pragma unroll
        for (int nt = 0; nt < 2; nt++) { accr[mt][nt] = zz; acci[mt][nt] = zz; }
    const uint4* H4 = (const uint4*)Hfrag;
    for (int kk = 0; kk < 8; kk++) {
        bf16x8 hm[2];
#pragma unroll
        for (int mt = 0; mt < 2; mt++) {
            int mtg = half*8 + w*2 + mt;
            hm[mt] = __builtin_bit_cast(bf16x8, H4[((size_t)kk*16 + mtg)*64 + lane]);
        }
        bf16x8 zr[2], zi_[2];
#pragma unroll
        for (int nt = 0; nt < 2; nt++) {
            int b = nt*16 + lo;
            int du = b*32 + ((kk*4 + hi) ^ (b & 7));
            zr[nt]  = __builtin_bit_cast(bf16x8, lz[0][du]);
            zi_[nt] = __builtin_bit_cast(bf16x8, lz[1][du]);
        }
#pragma unroll
        for (int mt = 0; mt < 2; mt++)
#pragma unroll
            for (int nt = 0; nt < 2; nt++) {
                accr[mt][nt] = __builtin_amdgcn_mfma_f32_16x16x32_bf16(hm[mt], zr[nt],  accr[mt][nt], 0, 0, 0);
                acci[mt][nt] = __builtin_amdgcn_mfma_f32_16x16x32_bf16(hm[mt], zi_[nt], acci[mt][nt], 0, 0, 0);
            }
    }
#pragma unroll
    for (int mt = 0; mt < 2; mt++)
#pragma unroll
        for (int nt = 0; nt < 2; nt++) {
            int o0 = half*128 + w*32 + mt*16 + hi*4;
            int b  = nt*16 + lo;
#pragma unroll
            for (int jj = 0; jj < 4; jj++) {
                wxh[((size_t)f*NCH + o0 + jj)*NB + b] =
                    make_float2(accr[mt][nt][jj], acci[mt][nt][jj]);
            }
        }
}

// ---------------- pass I: complex ifft along i: G[j][ob][r] ----------------
__global__ __launch_bounds__(256) void ifft_i(const float2* __restrict__ wxh, float2* __restrict__ G) {
    int j = blockIdx.x >> 5, obc = blockIdx.x & 31;
    int ob = obc * 256 + threadIdx.x;
    __shared__ float2 wt[32];
    if (threadIdx.x < 32) {
        float ph = 2.f * PI_F * (float)threadIdx.x / 32.f;
        wt[threadIdx.x] = make_float2(cosf(ph), sinf(ph));
    }
    __syncthreads();
    float2 Gacc[32];
#pragma unroll
    for (int r = 0; r < 32; r++) Gacc[r] = make_float2(0.f, 0.f);
    for (int i = 0; i < 32; i++) {
        float2 Y = wxh[((size_t)(i * 17 + j)) * 8192 + ob];
        int ir = 0;
#pragma unroll
        for (int r = 0; r < 32; r++) {
            float2 e = wt[ir];
            Gacc[r].x += Y.x*e.x - Y.y*e.y;
            Gacc[r].y += Y.x*e.y + Y.y*e.x;
            ir = (ir + i) & 31;
        }
    }
    float2* gp = G + ((size_t)j * 8192 + ob) * 32;
#pragma unroll
    for (int r = 0; r < 32; r++)
        gp[r] = make_float2(Gacc[r].x * (1.f/32.f), Gacc[r].y * (1.f/32.f));
}

// ---------------- pass II: irfft along j + bias -> out[b][o][r][s] ----------------
__global__ __launch_bounds__(256) void irfft_j(const float2* __restrict__ G,
                                               const float* __restrict__ bias,
                                               float* __restrict__ out) {
    int gid = blockIdx.x * 256 + threadIdx.x;
    int ob = gid >> 5, r = gid & 31;
    int o = ob >> 5, b = ob & 31;
    __shared__ float2 wt[32];
    if (threadIdx.x < 32) {
        float ph = 2.f * PI_F * (float)threadIdx.x / 32.f;
        wt[threadIdx.x] = make_float2(cosf(ph), sinf(ph));
    }
    __syncthreads();
    float2 Gv[17];
#pragma unroll
    for (int jj = 0; jj < 17; jj++) Gv[jj] = G[((size_t)jj * 8192 + ob) * 32 + r];
    float y[32];
    float g0 = Gv[0].x, g16 = Gv[16].x;
#pragma unroll
    for (int s = 0; s < 32; s++) y[s] = g0 + ((s & 1) ? -g16 : g16);
#pragma unroll
    for (int jj = 1; jj < 16; jj++) {
        int js = 0;
#pragma unroll
        for (int s = 0; s < 32; s++) {
            float2 e = wt[js];
            y[s] += 2.f * (Gv[jj].x * e.x - Gv[jj].y * e.y);
            js = (js + jj) & 31;
        }
    }
    float bv = bias[o];
    float* op = out + ((size_t)(b * NCH + o) * 32 + r) * 32;
#pragma unroll
    for (int s = 0; s < 32; s++) op[s] = y[s] * (1.f/32.f) + bv;
}

extern "C" void kernel_launch(void* const* d_in, const int* in_sizes, int n_in,
                              void* d_out, int out_size, void* d_ws, size_t ws_size,
                              hipStream_t stream) {
    (void)in_sizes; (void)n_in; (void)out_size;
    if (ws_size < WS_NEED) return;

    const float* x     = (const float*)d_in[0];
    const float* w     = (const float*)d_in[1];
    const float* alpha = (const float*)d_in[2];
    const float* H     = (const float*)d_in[3];
    const float* bias  = (const float*)d_in[4];
    float* out = (float*)d_out;

    char* ws = (char*)d_ws;
    unsigned short* Afrag = (unsigned short*)(ws + OFF_AFRAG);
    unsigned short* zbr   = (unsigned short*)(ws + OFF_ZBR);   // also wx real
    unsigned short* zbi   = (unsigned short*)(ws + OFF_ZBI);
    unsigned short* tbr   = (unsigned short*)(ws + OFF_TBR);
    unsigned short* tbi   = (unsigned short*)(ws + OFF_TBI);
    float* z32r = (float*)(ws + OFF_Z32R);
    float* z32i = (float*)(ws + OFF_Z32I);
    float2* wxh = (float2*)(ws + OFF_WXH);   // aliases tmp
    float2* tmp = (float2*)(ws + OFF_WXH);
    float2* G   = (float2*)(ws + OFF_AFRAG); // aliases Afrag (dead after passes)
    unsigned short* Hfrag = (unsigned short*)(ws + OFF_HFRAG);
    float* red = (float*)(ws + OFF_RED);
    float* sig = red + 256;

    norm_part<<<256, 256, 0, stream>>>(w, red);
    norm_final<<<1, 256, 0, stream>>>(red, alpha, sig);
    hfrag_build<<<dim3(8, 16), 64, 0, stream>>>(H, Hfrag);

    rfft2_reg<<<4096, 64, 0, stream>>>(x, tmp);
    transpose_z<<<dim3(8, 17, 32), 256, 0, stream>>>(tmp, z32r, z32i, zbr, zbi);

    for (int ch = 0; ch < 2; ch++) {
        int f0 = ch * FPC;
        a_build_frag<<<dim3(16, 8, 4), 256, 0, stream>>>(w, sig, Afrag, f0);
        neum_pass<1><<<FPC*2, 256, 0, stream>>>(Afrag, zbr, zbi, z32r, z32i, tbr, tbi, f0);
        neum_pass<2><<<FPC*2, 256, 0, stream>>>(Afrag, tbr, tbi, z32r, z32i, zbr, zbi, f0);
        pass_h<<<FPC*2, 256, 0, stream>>>(Hfrag, zbr, zbi, wxh, f0);
    }

    ifft_i<<<544, 256, 0, stream>>>(wxh, G);
    irfft_j<<<1024, 256, 0, stream>>>(G, bias, out);
}

// Round 7
// 297.689 us; speedup vs baseline: 2.1032x; 1.0965x over previous
//
#include <hip/hip_runtime.h>
#include <cstddef>

#define PI_F 3.14159265358979323846f

#define NCH 256   // C
#define NB  32    // B
#define NF  544   // n*(n/2+1),  f = i*17 + j
#define FPC 272   // freqs per A-chunk (2 chunks)

typedef short  bf16x8 __attribute__((ext_vector_type(8)));
typedef float  f32x4  __attribute__((ext_vector_type(4)));

// ---- workspace layout (bytes) ----
#define SZ_AFRAG ((size_t)FPC*8*16*2*1024)      // 71,303,168  (A fragments; G aliases here later)
#define SZ_PLANE ((size_t)NF*NB*NCH*2)          // 8,912,896   (bf16 plane [f][b][c])
#define SZ_P32   ((size_t)NF*NB*NCH*4)          // 17,825,792  (fp32 plane)
#define SZ_WXH   ((size_t)NF*8192*8)            // 35,651,584  (float2 [f][o*32+b]; also tmp)
#define OFF_AFRAG ((size_t)0)
#define OFF_ZBR  (OFF_AFRAG + SZ_AFRAG)         // z bf16 real; later wx real
#define OFF_ZBI  (OFF_ZBR + SZ_PLANE)
#define OFF_TBR  (OFF_ZBI + SZ_PLANE)
#define OFF_TBI  (OFF_TBR + SZ_PLANE)
#define OFF_Z32R (OFF_TBI + SZ_PLANE)
#define OFF_Z32I (OFF_Z32R + SZ_P32)
#define OFF_WXH  (OFF_Z32I + SZ_P32)            // wxh float2; also tmp (rfft2 out)
#define OFF_HFRAG (OFF_WXH + SZ_WXH)
#define SZ_HFRAG ((size_t)8*16*1024)            // 131,072
#define OFF_RED  (OFF_HFRAG + SZ_HFRAG)
#define WS_NEED  (OFF_RED + (size_t)4096)       // ~178.4 MB (proven available)

// 32-point twiddle tables, positive phase: COS32[k]=cos(2pi k/32), SIN32[k]=sin(2pi k/32)
__device__ constexpr float COS32[32] = {
     1.0000000000f,  0.9807852804f,  0.9238795325f,  0.8314696123f,
     0.7071067812f,  0.5555702330f,  0.3826834324f,  0.1950903220f,
     0.0000000000f, -0.1950903220f, -0.3826834324f, -0.5555702330f,
    -0.7071067812f, -0.8314696123f, -0.9238795325f, -0.9807852804f,
    -1.0000000000f, -0.9807852804f, -0.9238795325f, -0.8314696123f,
    -0.7071067812f, -0.5555702330f, -0.3826834324f, -0.1950903220f,
    -0.0000000000f,  0.1950903220f,  0.3826834324f,  0.5555702330f,
     0.7071067812f,  0.8314696123f,  0.9238795325f,  0.9807852804f };
__device__ constexpr float SIN32[32] = {
     0.0000000000f,  0.1950903220f,  0.3826834324f,  0.5555702330f,
     0.7071067812f,  0.8314696123f,  0.9238795325f,  0.9807852804f,
     1.0000000000f,  0.9807852804f,  0.9238795325f,  0.8314696123f,
     0.7071067812f,  0.5555702330f,  0.3826834324f,  0.1950903220f,
     0.0000000000f, -0.1950903220f, -0.3826834324f, -0.5555702330f,
    -0.7071067812f, -0.8314696123f, -0.9238795325f, -0.9807852804f,
    -1.0000000000f, -0.9807852804f, -0.9238795325f, -0.8314696123f,
    -0.7071067812f, -0.5555702330f, -0.3826834324f, -0.1950903220f };

__device__ __forceinline__ unsigned short f2bf(float x) {
    unsigned int u = __float_as_uint(x);
    u += 0x7FFFu + ((u >> 16) & 1u);            // RNE
    return (unsigned short)(u >> 16);
}
__device__ __forceinline__ unsigned int pack2(float a, float b) {
    return (unsigned int)f2bf(a) | ((unsigned int)f2bf(b) << 16);
}

// ---------------- norm of wfft (closed form via Parseval) ----------------
__global__ void norm_part(const float* __restrict__ w, float* __restrict__ red) {
    int idx = blockIdx.x * 256 + threadIdx.x;
    const float* wp = w + (size_t)idx * 9;
    float s2 = 0.f, aa = 0.f, bb = 0.f;
#pragma unroll
    for (int u = 0; u < 3; u++) {
        float w0 = wp[u*3+0], w1 = wp[u*3+1], w2 = wp[u*3+2];
        s2 += w0*w0 + w1*w1 + w2*w2;
        float au = w0 + w1 + w2, bu = w0 - w1 + w2;
        aa += au*au; bb += bu*bu;
    }
    float p = 512.f*s2 + 16.f*(aa + bb);
    __shared__ float sm[256];
    sm[threadIdx.x] = p; __syncthreads();
    for (int s = 128; s > 0; s >>= 1) {
        if (threadIdx.x < s) sm[threadIdx.x] += sm[threadIdx.x + s];
        __syncthreads();
    }
    if (threadIdx.x == 0) red[blockIdx.x] = sm[0];
}

__global__ void norm_final(const float* __restrict__ red, const float* __restrict__ alpha,
                           float* __restrict__ sig) {
    __shared__ float sm[256];
    sm[threadIdx.x] = red[threadIdx.x]; __syncthreads();
    for (int s = 128; s > 0; s >>= 1) {
        if (threadIdx.x < s) sm[threadIdx.x] += sm[threadIdx.x + s];
        __syncthreads();
    }
    if (threadIdx.x == 0) sig[0] = alpha[0] / sqrtf(sm[0]);
}

// ---------------- H fragments (A-operand: m=o, k=c) ----------------
__global__ void hfrag_build(const float* __restrict__ H, unsigned short* __restrict__ Hfrag) {
    int kk = blockIdx.x, mt = blockIdx.y, lane = threadIdx.x;   // 64 threads
    int o = mt*16 + (lane & 15), c0 = kk*32 + (lane >> 4)*8;
    const float* hp = H + (size_t)o*NCH + c0;
    uint4 u;
    u.x = pack2(hp[0], hp[1]); u.y = pack2(hp[2], hp[3]);
    u.z = pack2(hp[4], hp[5]); u.w = pack2(hp[6], hp[7]);
    ((uint4*)Hfrag)[((size_t)kk*16 + mt)*64 + lane] = u;
}

// ---------------- rfft2: register-resident DFT, 8 tiles per 256-thread block ----------------
__global__ __launch_bounds__(256) void rfft2_reg(const float* __restrict__ x,
                                                 float2* __restrict__ tmp)
{
    __shared__ float2 T[8][544];       // [half][r*17+j], ~35 KB
    __shared__ float wc[32], wsn[32];
    int t = threadIdx.x;
    int half = t >> 5, lane = t & 31;
    int cb = blockIdx.x * 8 + half;    // tile index in tmp order: cb = c*32 + b
    int c = cb >> 5, b = cb & 31;
    if (t < 32) { wc[t] = COS32[t]; wsn[t] = SIN32[t]; }
    // load row r=lane of this tile into registers
    float xr[32];
    const float* xp = x + ((size_t)(b * NCH + c)) * 1024 + lane * 32;
#pragma unroll
    for (int q = 0; q < 8; q++) {
        float4 v = *(const float4*)(xp + q*4);
        xr[q*4+0] = v.x; xr[q*4+1] = v.y; xr[q*4+2] = v.z; xr[q*4+3] = v.w;
    }
    // step 1: T[r=lane][j] = sum_s x[r,s] e^{-2pi i j s/32}   (constant twiddles)
#pragma unroll
    for (int j = 0; j < 17; j++) {
        float ax = 0.f, ay = 0.f;
#pragma unroll
        for (int s = 0; s < 32; s++) {
            int m = (j * s) & 31;
            ax += xr[s] * COS32[m];
            ay -= xr[s] * SIN32[m];
        }
        T[half][lane*17 + j] = make_float2(ax, ay);
    }
    __syncthreads();
    // preload per-lane (i = lane) twiddles: w[(i*r)&31] (distinct index -> distinct bank)
    float wr_[32], wi_[32];
#pragma unroll
    for (int r = 0; r < 32; r++) {
        int m = (lane * r) & 31;
        wr_[r] = wc[m]; wi_[r] = wsn[m];
    }
    // step 2: z[i=lane][j] = sum_r e^{-2pi i i r/32} T[r][j]  (T reads broadcast)
    float2* op = tmp + (size_t)cb * 544 + lane * 17;
#pragma unroll
    for (int j = 0; j < 17; j++) {
        float ax = 0.f, ay = 0.f;
#pragma unroll
        for (int r = 0; r < 32; r++) {
            float2 tv = T[half][r*17 + j];
            ax += tv.x * wr_[r] + tv.y * wi_[r];
            ay += tv.y * wr_[r] - tv.x * wi_[r];
        }
        op[j] = make_float2(ax, ay);
    }
}

// ---------------- transpose tmp[cb][f] -> plane layouts [f][b][c] (fp32 + bf16) ----------------
__global__ __launch_bounds__(256) void transpose_z(const float2* __restrict__ tmp,
        float* __restrict__ z32r, float* __restrict__ z32i,
        unsigned short* __restrict__ zbr, unsigned short* __restrict__ zbi)
{
    __shared__ float2 tile[32][33];
    int ct = blockIdx.x, ft = blockIdx.y, b = blockIdx.z;
    int t = threadIdx.x;
#pragma unroll
    for (int it = 0; it < 4; it++) {
        int idx = t + it*256; int cl = idx >> 5, fl = idx & 31;
        tile[cl][fl] = tmp[((size_t)((ct*32 + cl)*32 + b))*544 + ft*32 + fl];
    }
    __syncthreads();
#pragma unroll
    for (int it = 0; it < 4; it++) {
        int idx = t + it*256; int fl = idx >> 5, cl = idx & 31;
        float2 v = tile[cl][fl];
        size_t zi_ = ((size_t)(ft*32 + fl)*NB + b)*NCH + ct*32 + cl;
        z32r[zi_] = v.x; z32i[zi_] = v.y;
        zbr[zi_] = f2bf(v.x); zbi[zi_] = f2bf(v.y);
    }
}

// ---------------- A-build into MFMA fragment order (table-lookup form) ----------------
__global__ __launch_bounds__(256) void a_build_frag(const float* __restrict__ w,
        const float* __restrict__ sig, unsigned short* __restrict__ Afrag, int f0)
{
    __shared__ float2 wtab[32];
    __shared__ unsigned short lar[512], lai[512];
    int t = threadIdx.x;
    if (t < 32) {
        float ph = -2.f * PI_F * (float)t / 32.f;
        wtab[t] = make_float2(cosf(ph), sinf(ph));
    }
    int mt = blockIdx.x, kk = blockIdx.y, fs = blockIdx.z;
    int c = mt*16 + (t & 15), cpl = t >> 4;
    int cpA = kk*32 + cpl, cpB = cpA + 16;
    float ua[9], va[9], ub[9], vb[9];
    {
        const float* pa1 = w + ((size_t)c*NCH + cpA)*9;
        const float* pb1 = w + ((size_t)c*NCH + cpB)*9;
        const float* pa2 = w + ((size_t)cpA*NCH + c)*9;
        const float* pb2 = w + ((size_t)cpB*NCH + c)*9;
#pragma unroll
        for (int q = 0; q < 9; q++) {
            float w1a = pa1[q], w2a = pa2[q], w1b = pb1[q], w2b = pb2[q];
            ua[q] = w1a - w2a; va[q] = w1a + w2a;
            ub[q] = w1b - w2b; vb[q] = w1b + w2b;
        }
    }
    float s = sig[0];
    int la_ = ((c & 15) + 16*(cpl>>3))*8 + (cpl & 7);
    int lb_ = la_ + 32*8;
    __syncthreads();
    for (int fl = fs*68; fl < fs*68 + 68; fl++) {
        int f = f0 + fl;
        int i = f / 17, jj = f - i * 17;    // f = i*17 + j ordering
        int m_[9];
        m_[0] = (i + jj) & 31;  m_[1] = i;             m_[2] = (i - jj) & 31;
        m_[3] = jj;             m_[4] = 0;             m_[5] = (32 - jj) & 31;
        m_[6] = (jj - i) & 31;  m_[7] = (32 - i) & 31; m_[8] = (64 - i - jj) & 31;
        float ArA = 0.f, AiA = 0.f, ArB = 0.f, AiB = 0.f;
#pragma unroll
        for (int q = 0; q < 9; q++) {
            float2 P = wtab[m_[q]];
            ArA += ua[q] * P.x; AiA += va[q] * P.y;
            ArB += ub[q] * P.x; AiB += vb[q] * P.y;
        }
        lar[la_] = f2bf(s*ArA); lai[la_] = f2bf(s*AiA);
        lar[lb_] = f2bf(s*ArB); lai[lb_] = f2bf(s*AiB);
        __syncthreads();
        size_t bch = (((size_t)fl*8 + kk)*16 + mt)*256;   // uint2 units
        ((uint2*)Afrag)[bch + t] = (t < 128) ? ((const uint2*)lar)[t]
                                             : ((const uint2*)lai)[t - 128];
        __syncthreads();
    }
}

// ---------------- Neumann pass via MFMA ----------------
// MODE 1: out = z32 - acc   (t = z - A z)
// MODE 2: out = z32 - 2*acc (wx = z - 2 A t)
template<int MODE>
__global__ __launch_bounds__(256) void neum_pass(
    const unsigned short* __restrict__ Afrag,
    const unsigned short* __restrict__ BR, const unsigned short* __restrict__ BI,
    const float* __restrict__ z32r, const float* __restrict__ z32i,
    unsigned short* __restrict__ outR, unsigned short* __restrict__ outI, int f0)
{
    __shared__ uint4 lz[2][1024];   // 32 KB, swizzled
    int fl = blockIdx.x >> 1, half = blockIdx.x & 1;
    int f = f0 + fl;
    int t = threadIdx.x;
    const uint4* s0 = (const uint4*)(BR + (size_t)f*8192);
    const uint4* s1 = (const uint4*)(BI + (size_t)f*8192);
    for (int u = t; u < 1024; u += 256) {
        int b = u >> 5, o16 = u & 31;
        int du = b*32 + (o16 ^ (b & 7));
        lz[0][du] = s0[u];
        lz[1][du] = s1[u];
    }
    __syncthreads();
    int w = t >> 6, lane = t & 63, lo = lane & 15, hi = lane >> 4;
    f32x4 accr[2][2], acci[2][2];
    f32x4 zz = {0.f, 0.f, 0.f, 0.f};
#pragma unroll
    for (int mt = 0; mt < 2; mt++)
#pragma unroll
        for (int nt = 0; nt < 2; nt++) { accr[mt][nt] = zz; acci[mt][nt] = zz; }
    const uint4* A4 = (const uint4*)Afrag;
    for (int kk = 0; kk < 8; kk++) {
        bf16x8 ar[2], ai[2], ain[2];
#pragma unroll
        for (int mt = 0; mt < 2; mt++) {
            int mtg = half*8 + w*2 + mt;
            size_t idx = ((((size_t)fl*8 + kk)*16 + mtg)*2)*64 + lane;
            uint4 va = A4[idx], vb = A4[idx + 64];
            ar[mt] = __builtin_bit_cast(bf16x8, va);
            ai[mt] = __builtin_bit_cast(bf16x8, vb);
            uint4 vn = make_uint4(vb.x ^ 0x80008000u, vb.y ^ 0x80008000u,
                                  vb.z ^ 0x80008000u, vb.w ^ 0x80008000u);
            ain[mt] = __builtin_bit_cast(bf16x8, vn);
        }
        bf16x8 zr[2], zi_[2];
#pragma unroll
        for (int nt = 0; nt < 2; nt++) {
            int b = nt*16 + lo;
            int du = b*32 + ((kk*4 + hi) ^ (b & 7));
            zr[nt]  = __builtin_bit_cast(bf16x8, lz[0][du]);
            zi_[nt] = __builtin_bit_cast(bf16x8, lz[1][du]);
        }
#pragma unroll
        for (int mt = 0; mt < 2; mt++)
#pragma unroll
            for (int nt = 0; nt < 2; nt++) {
                accr[mt][nt] = __builtin_amdgcn_mfma_f32_16x16x32_bf16(ar[mt],  zr[nt],  accr[mt][nt], 0, 0, 0);
                accr[mt][nt] = __builtin_amdgcn_mfma_f32_16x16x32_bf16(ain[mt], zi_[nt], accr[mt][nt], 0, 0, 0);
                acci[mt][nt] = __builtin_amdgcn_mfma_f32_16x16x32_bf16(ar[mt],  zi_[nt], acci[mt][nt], 0, 0, 0);
                acci[mt][nt] = __builtin_amdgcn_mfma_f32_16x16x32_bf16(ai[mt],  zr[nt],  acci[mt][nt], 0, 0, 0);
            }
    }
#pragma unroll
    for (int mt = 0; mt < 2; mt++)
#pragma unroll
        for (int nt = 0; nt < 2; nt++) {
            int c0 = half*128 + w*32 + mt*16 + hi*4;
            int b  = nt*16 + lo;
            size_t zb = ((size_t)f*NB + b)*NCH + c0;
            float vr[4], vi[4];
#pragma unroll
            for (int jj = 0; jj < 4; jj++) {
                float zrv = z32r[zb + jj], ziv = z32i[zb + jj];
                float cr = accr[mt][nt][jj], ci = acci[mt][nt][jj];
                if (MODE == 1) { vr[jj] = zrv - cr;      vi[jj] = ziv - ci; }
                else           { vr[jj] = zrv - 2.f*cr;  vi[jj] = ziv - 2.f*ci; }
            }
            *(uint2*)(outR + zb) = make_uint2(pack2(vr[0], vr[1]), pack2(vr[2], vr[3]));
            *(uint2*)(outI + zb) = make_uint2(pack2(vi[0], vi[1]), pack2(vi[2], vi[3]));
        }
}

// ---------------- H pass via MFMA: wxh[f][o*32+b] = sum_c H[o,c] wx[f,c,b] ----------------
__global__ __launch_bounds__(256) void pass_h(
    const unsigned short* __restrict__ Hfrag,
    const unsigned short* __restrict__ BR, const unsigned short* __restrict__ BI,
    float2* __restrict__ wxh, int f0)
{
    __shared__ uint4 lz[2][1024];
    int fl = blockIdx.x >> 1, half = blockIdx.x & 1;
    int f = f0 + fl;
    int t = threadIdx.x;
    const uint4* s0 = (const uint4*)(BR + (size_t)f*8192);
    const uint4* s1 = (const uint4*)(BI + (size_t)f*8192);
    for (int u = t; u < 1024; u += 256) {
        int b = u >> 5, o16 = u & 31;
        int du = b*32 + (o16 ^ (b & 7));
        lz[0][du] = s0[u];
        lz[1][du] = s1[u];
    }
    __syncthreads();
    int w = t >> 6, lane = t & 63, lo = lane & 15, hi = lane >> 4;
    f32x4 accr[2][2], acci[2][2];
    f32x4 zz = {0.f, 0.f, 0.f, 0.f};
#pragma unroll
    for (int mt = 0; mt < 2; mt++)
#pragma unroll
        for (int nt = 0; nt < 2; nt++) { accr[mt][nt] = zz; acci[mt][nt] = zz; }
    const uint4* H4 = (const uint4*)Hfrag;
    for (int kk = 0; kk < 8; kk++) {
        bf16x8 hm[2];
#pragma unroll
        for (int mt = 0; mt < 2; mt++) {
            int mtg = half*8 + w*2 + mt;
            hm[mt] = __builtin_bit_cast(bf16x8, H4[((size_t)kk*16 + mtg)*64 + lane]);
        }
        bf16x8 zr[2], zi_[2];
#pragma unroll
        for (int nt = 0; nt < 2; nt++) {
            int b = nt*16 + lo;
            int du = b*32 + ((kk*4 + hi) ^ (b & 7));
            zr[nt]  = __builtin_bit_cast(bf16x8, lz[0][du]);
            zi_[nt] = __builtin_bit_cast(bf16x8, lz[1][du]);
        }
#pragma unroll
        for (int mt = 0; mt < 2; mt++)
#pragma unroll
            for (int nt = 0; nt < 2; nt++) {
                accr[mt][nt] = __builtin_amdgcn_mfma_f32_16x16x32_bf16(hm[mt], zr[nt],  accr[mt][nt], 0, 0, 0);
                acci[mt][nt] = __builtin_amdgcn_mfma_f32_16x16x32_bf16(hm[mt], zi_[nt], acci[mt][nt], 0, 0, 0);
            }
    }
#pragma unroll
    for (int mt = 0; mt < 2; mt++)
#pragma unroll
        for (int nt = 0; nt < 2; nt++) {
            int o0 = half*128 + w*32 + mt*16 + hi*4;
            int b  = nt*16 + lo;
#pragma unroll
            for (int jj = 0; jj < 4; jj++) {
                wxh[((size_t)f*NCH + o0 + jj)*NB + b] =
                    make_float2(accr[mt][nt][jj], acci[mt][nt][jj]);
            }
        }
}

// ---------------- pass I: complex ifft along i -> G[j][r][ob] (coalesced stores) ----------------
template<int RH>
__device__ __forceinline__ void ifft_i_body(const float2* __restrict__ wxh,
                                            float2* __restrict__ G, int j, int ob)
{
    float2 Gacc[16];
#pragma unroll
    for (int rr = 0; rr < 16; rr++) Gacc[rr] = make_float2(0.f, 0.f);
#pragma unroll
    for (int i = 0; i < 32; i++) {
        float2 Y = wxh[((size_t)(i * 17 + j)) * 8192 + ob];
#pragma unroll
        for (int rr = 0; rr < 16; rr++) {
            int m = (i * (RH * 16 + rr)) & 31;     // compile-time constant
            Gacc[rr].x += Y.x*COS32[m] - Y.y*SIN32[m];
            Gacc[rr].y += Y.x*SIN32[m] + Y.y*COS32[m];
        }
    }
#pragma unroll
    for (int rr = 0; rr < 16; rr++) {
        G[((size_t)(j*32 + RH*16 + rr))*8192 + ob] =
            make_float2(Gacc[rr].x * (1.f/32.f), Gacc[rr].y * (1.f/32.f));
    }
}

__global__ __launch_bounds__(256) void ifft_i(const float2* __restrict__ wxh, float2* __restrict__ G) {
    int bid = blockIdx.x;
    int j   = bid >> 6;          // 0..16
    int rh  = (bid >> 5) & 1;    // 0..1
    int obc = bid & 31;          // 0..31
    int ob  = obc * 256 + threadIdx.x;
    if (rh == 0) ifft_i_body<0>(wxh, G, j, ob);
    else         ifft_i_body<1>(wxh, G, j, ob);
}

// ---------------- pass II: irfft along j + bias -> out[b][o][r][s] ----------------
// thread -> (r, ob): r = gid>>13, ob = gid&8191  (G reads coalesced in [j][r][ob])
__global__ __launch_bounds__(256) void irfft_j(const float2* __restrict__ G,
                                               const float* __restrict__ bias,
                                               float* __restrict__ out) {
    int gid = blockIdx.x * 256 + threadIdx.x;
    int r = gid >> 13, ob = gid & 8191;
    int o = ob >> 5, b = ob & 31;
    float2 Gv[17];
#pragma unroll
    for (int jj = 0; jj < 17; jj++)
        Gv[jj] = G[((size_t)(jj*32 + r))*8192 + ob];
    float y[32];
    float g0 = Gv[0].x, g16 = Gv[16].x;
#pragma unroll
    for (int s = 0; s < 32; s++) y[s] = g0 + ((s & 1) ? -g16 : g16);
#pragma unroll
    for (int jj = 1; jj < 16; jj++) {
#pragma unroll
        for (int s = 0; s < 32; s++) {
            int m = (jj * s) & 31;                 // compile-time constant
            y[s] += 2.f * (Gv[jj].x * COS32[m] - Gv[jj].y * SIN32[m]);
        }
    }
    float bv = bias[o];
    float* op = out + ((size_t)(b * NCH + o) * 32 + r) * 32;
#pragma unroll
    for (int s = 0; s < 32; s++) op[s] = y[s] * (1.f/32.f) + bv;
}

extern "C" void kernel_launch(void* const* d_in, const int* in_sizes, int n_in,
                              void* d_out, int out_size, void* d_ws, size_t ws_size,
                              hipStream_t stream) {
    (void)in_sizes; (void)n_in; (void)out_size;
    if (ws_size < WS_NEED) return;

    const float* x     = (const float*)d_in[0];
    const float* w     = (const float*)d_in[1];
    const float* alpha = (const float*)d_in[2];
    const float* H     = (const float*)d_in[3];
    const float* bias  = (const float*)d_in[4];
    float* out = (float*)d_out;

    char* ws = (char*)d_ws;
    unsigned short* Afrag = (unsigned short*)(ws + OFF_AFRAG);
    unsigned short* zbr   = (unsigned short*)(ws + OFF_ZBR);   // also wx real
    unsigned short* zbi   = (unsigned short*)(ws + OFF_ZBI);
    unsigned short* tbr   = (unsigned short*)(ws + OFF_TBR);
    unsigned short* tbi   = (unsigned short*)(ws + OFF_TBI);
    float* z32r = (float*)(ws + OFF_Z32R);
    float* z32i = (float*)(ws + OFF_Z32I);
    float2* wxh = (float2*)(ws + OFF_WXH);   // aliases tmp
    float2* tmp = (float2*)(ws + OFF_WXH);
    float2* G   = (float2*)(ws + OFF_AFRAG); // aliases Afrag (dead after passes)
    unsigned short* Hfrag = (unsigned short*)(ws + OFF_HFRAG);
    float* red = (float*)(ws + OFF_RED);
    float* sig = red + 256;

    norm_part<<<256, 256, 0, stream>>>(w, red);
    norm_final<<<1, 256, 0, stream>>>(red, alpha, sig);
    hfrag_build<<<dim3(8, 16), 64, 0, stream>>>(H, Hfrag);

    rfft2_reg<<<1024, 256, 0, stream>>>(x, tmp);
    transpose_z<<<dim3(8, 17, 32), 256, 0, stream>>>(tmp, z32r, z32i, zbr, zbi);

    for (int ch = 0; ch < 2; ch++) {
        int f0 = ch * FPC;
        a_build_frag<<<dim3(16, 8, 4), 256, 0, stream>>>(w, sig, Afrag, f0);
        neum_pass<1><<<FPC*2, 256, 0, stream>>>(Afrag, zbr, zbi, z32r, z32i, tbr, tbi, f0);
        neum_pass<2><<<FPC*2, 256, 0, stream>>>(Afrag, tbr, tbi, z32r, z32i, zbr, zbi, f0);
        pass_h<<<FPC*2, 256, 0, stream>>>(Hfrag, zbr, zbi, wxh, f0);
    }

    ifft_i<<<1088, 256, 0, stream>>>(wxh, G);
    irfft_j<<<1024, 256, 0, stream>>>(G, bias, out);
}

// Round 8
// 263.248 us; speedup vs baseline: 2.3784x; 1.1308x over previous
//
#include <hip/hip_runtime.h>
#include <cstddef>

#define PI_F 3.14159265358979323846f

#define NCH 256   // C
#define NB  32    // B
#define NF  544   // n*(n/2+1),  f = i*17 + j
#define FPC 272   // freqs per A-chunk (2 chunks)

typedef short  bf16x8 __attribute__((ext_vector_type(8)));
typedef float  f32x4  __attribute__((ext_vector_type(4)));

// ---- workspace layout (bytes) ----
#define SZ_AFRAG ((size_t)FPC*8*16*2*1024)      // 71,303,168  (A fragments; G aliases here later)
#define SZ_PLANE ((size_t)NF*NB*NCH*2)          // 8,912,896   (bf16 plane [f][b][c])
#define SZ_P32   ((size_t)NF*NB*NCH*4)          // 17,825,792  (fp32 plane)
#define SZ_WXH   ((size_t)NF*8192*8)            // 35,651,584  (float2 [f][o*32+b]; also tmp)
#define OFF_AFRAG ((size_t)0)
#define OFF_ZBR  (OFF_AFRAG + SZ_AFRAG)
#define OFF_ZBI  (OFF_ZBR + SZ_PLANE)
#define OFF_TBR  (OFF_ZBI + SZ_PLANE)
#define OFF_TBI  (OFF_TBR + SZ_PLANE)
#define OFF_Z32R (OFF_TBI + SZ_PLANE)
#define OFF_Z32I (OFF_Z32R + SZ_P32)
#define OFF_WXH  (OFF_Z32I + SZ_P32)            // wxh float2; also tmp (rfft2 out)
#define OFF_HFRAG (OFF_WXH + SZ_WXH)
#define SZ_HFRAG ((size_t)8*16*1024)            // 131,072
#define OFF_RED  (OFF_HFRAG + SZ_HFRAG)
#define WS_NEED  (OFF_RED + (size_t)4096)       // ~178.4 MB (proven available)

// 32-point twiddle tables, positive phase: COS32[k]=cos(2pi k/32), SIN32[k]=sin(2pi k/32)
__device__ constexpr float COS32[32] = {
     1.0000000000f,  0.9807852804f,  0.9238795325f,  0.8314696123f,
     0.7071067812f,  0.5555702330f,  0.3826834324f,  0.1950903220f,
     0.0000000000f, -0.1950903220f, -0.3826834324f, -0.5555702330f,
    -0.7071067812f, -0.8314696123f, -0.9238795325f, -0.9807852804f,
    -1.0000000000f, -0.9807852804f, -0.9238795325f, -0.8314696123f,
    -0.7071067812f, -0.5555702330f, -0.3826834324f, -0.1950903220f,
    -0.0000000000f,  0.1950903220f,  0.3826834324f,  0.5555702330f,
     0.7071067812f,  0.8314696123f,  0.9238795325f,  0.9807852804f };
__device__ constexpr float SIN32[32] = {
     0.0000000000f,  0.1950903220f,  0.3826834324f,  0.5555702330f,
     0.7071067812f,  0.8314696123f,  0.9238795325f,  0.9807852804f,
     1.0000000000f,  0.9807852804f,  0.9238795325f,  0.8314696123f,
     0.7071067812f,  0.5555702330f,  0.3826834324f,  0.1950903220f,
     0.0000000000f, -0.1950903220f, -0.3826834324f, -0.5555702330f,
    -0.7071067812f, -0.8314696123f, -0.9238795325f, -0.9807852804f,
    -1.0000000000f, -0.9807852804f, -0.9238795325f, -0.8314696123f,
    -0.7071067812f, -0.5555702330f, -0.3826834324f, -0.1950903220f };

__device__ __forceinline__ unsigned short f2bf(float x) {
    unsigned int u = __float_as_uint(x);
    u += 0x7FFFu + ((u >> 16) & 1u);            // RNE
    return (unsigned short)(u >> 16);
}
__device__ __forceinline__ float bf2f(unsigned int h) {
    return __uint_as_float(h << 16);
}
__device__ __forceinline__ unsigned int pack2(float a, float b) {
    return (unsigned int)f2bf(a) | ((unsigned int)f2bf(b) << 16);
}

// ---------------- norm of wfft (closed form via Parseval) ----------------
__global__ void norm_part(const float* __restrict__ w, float* __restrict__ red) {
    int idx = blockIdx.x * 256 + threadIdx.x;
    const float* wp = w + (size_t)idx * 9;
    float s2 = 0.f, aa = 0.f, bb = 0.f;
#pragma unroll
    for (int u = 0; u < 3; u++) {
        float w0 = wp[u*3+0], w1 = wp[u*3+1], w2 = wp[u*3+2];
        s2 += w0*w0 + w1*w1 + w2*w2;
        float au = w0 + w1 + w2, bu = w0 - w1 + w2;
        aa += au*au; bb += bu*bu;
    }
    float p = 512.f*s2 + 16.f*(aa + bb);
    __shared__ float sm[256];
    sm[threadIdx.x] = p; __syncthreads();
    for (int s = 128; s > 0; s >>= 1) {
        if (threadIdx.x < s) sm[threadIdx.x] += sm[threadIdx.x + s];
        __syncthreads();
    }
    if (threadIdx.x == 0) red[blockIdx.x] = sm[0];
}

__global__ void norm_final(const float* __restrict__ red, const float* __restrict__ alpha,
                           float* __restrict__ sig) {
    __shared__ float sm[256];
    sm[threadIdx.x] = red[threadIdx.x]; __syncthreads();
    for (int s = 128; s > 0; s >>= 1) {
        if (threadIdx.x < s) sm[threadIdx.x] += sm[threadIdx.x + s];
        __syncthreads();
    }
    if (threadIdx.x == 0) sig[0] = alpha[0] / sqrtf(sm[0]);
}

// ---------------- H fragments (A-operand: m=o, k=c) ----------------
__global__ void hfrag_build(const float* __restrict__ H, unsigned short* __restrict__ Hfrag) {
    int kk = blockIdx.x, mt = blockIdx.y, lane = threadIdx.x;   // 64 threads
    int o = mt*16 + (lane & 15), c0 = kk*32 + (lane >> 4)*8;
    const float* hp = H + (size_t)o*NCH + c0;
    uint4 u;
    u.x = pack2(hp[0], hp[1]); u.y = pack2(hp[2], hp[3]);
    u.z = pack2(hp[4], hp[5]); u.w = pack2(hp[6], hp[7]);
    ((uint4*)Hfrag)[((size_t)kk*16 + mt)*64 + lane] = u;
}

// ---------------- rfft2: register-resident DFT, 8 tiles per 256-thread block ----------------
// step-2 uses w^{i(r+16)} = (-1)^i w^{ir}: halves twiddle VGPRs and cuts FMAs 25%.
__global__ __launch_bounds__(256) void rfft2_reg(const float* __restrict__ x,
                                                 float2* __restrict__ tmp)
{
    __shared__ float2 T[8][544];       // [half][r*17+j], ~35 KB
    __shared__ float wc[32], wsn[32];
    int t = threadIdx.x;
    int half = t >> 5, lane = t & 31;
    int cb = blockIdx.x * 8 + half;    // tile index in tmp order: cb = c*32 + b
    int c = cb >> 5, b = cb & 31;
    if (t < 32) { wc[t] = COS32[t]; wsn[t] = SIN32[t]; }
    // load row r=lane of this tile into registers
    float xr[32];
    const float* xp = x + ((size_t)(b * NCH + c)) * 1024 + lane * 32;
#pragma unroll
    for (int q = 0; q < 8; q++) {
        float4 v = *(const float4*)(xp + q*4);
        xr[q*4+0] = v.x; xr[q*4+1] = v.y; xr[q*4+2] = v.z; xr[q*4+3] = v.w;
    }
    // step 1: T[r=lane][j] = sum_s x[r,s] e^{-2pi i j s/32}   (constant twiddles)
#pragma unroll
    for (int j = 0; j < 17; j++) {
        float ax = 0.f, ay = 0.f;
#pragma unroll
        for (int s = 0; s < 32; s++) {
            int m = (j * s) & 31;
            ax += xr[s] * COS32[m];
            ay -= xr[s] * SIN32[m];
        }
        T[half][lane*17 + j] = make_float2(ax, ay);
    }
    __syncthreads();
    // per-lane (i = lane) twiddles for r<16 only
    float wr_[16], wi_[16];
#pragma unroll
    for (int r = 0; r < 16; r++) {
        int m = (lane * r) & 31;
        wr_[r] = wc[m]; wi_[r] = wsn[m];
    }
    float sgn = (lane & 1) ? -1.f : 1.f;    // (-1)^i
    // step 2: z[i=lane][j] = sum_{r<16} e^{-2pi i i r/32} (T[r][j] + (-1)^i T[r+16][j])
    float2* op = tmp + (size_t)cb * 544 + lane * 17;
#pragma unroll
    for (int j = 0; j < 17; j++) {
        float ax = 0.f, ay = 0.f;
#pragma unroll
        for (int r = 0; r < 16; r++) {
            float2 t1 = T[half][r*17 + j];
            float2 t2 = T[half][(r+16)*17 + j];
            float ex = fmaf(sgn, t2.x, t1.x);
            float ey = fmaf(sgn, t2.y, t1.y);
            ax += ex * wr_[r] + ey * wi_[r];
            ay += ey * wr_[r] - ex * wi_[r];
        }
        op[j] = make_float2(ax, ay);
    }
}

// ---------------- transpose tmp[cb][f] -> plane layouts [f][b][c] (fp32 + bf16) ----------------
__global__ __launch_bounds__(256) void transpose_z(const float2* __restrict__ tmp,
        float* __restrict__ z32r, float* __restrict__ z32i,
        unsigned short* __restrict__ zbr, unsigned short* __restrict__ zbi)
{
    __shared__ float2 tile[32][33];
    int ct = blockIdx.x, ft = blockIdx.y, b = blockIdx.z;
    int t = threadIdx.x;
#pragma unroll
    for (int it = 0; it < 4; it++) {
        int idx = t + it*256; int cl = idx >> 5, fl = idx & 31;
        tile[cl][fl] = tmp[((size_t)((ct*32 + cl)*32 + b))*544 + ft*32 + fl];
    }
    __syncthreads();
#pragma unroll
    for (int it = 0; it < 4; it++) {
        int idx = t + it*256; int fl = idx >> 5, cl = idx & 31;
        float2 v = tile[cl][fl];
        size_t zi_ = ((size_t)(ft*32 + fl)*NB + b)*NCH + ct*32 + cl;
        z32r[zi_] = v.x; z32i[zi_] = v.y;
        zbr[zi_] = f2bf(v.x); zbi[zi_] = f2bf(v.y);
    }
}

// ---------------- A-build into MFMA fragment order (table-lookup form) ----------------
__global__ __launch_bounds__(256) void a_build_frag(const float* __restrict__ w,
        const float* __restrict__ sig, unsigned short* __restrict__ Afrag, int f0)
{
    __shared__ float2 wtab[32];
    __shared__ unsigned short lar[512], lai[512];
    int t = threadIdx.x;
    if (t < 32) {
        float ph = -2.f * PI_F * (float)t / 32.f;
        wtab[t] = make_float2(cosf(ph), sinf(ph));
    }
    int mt = blockIdx.x, kk = blockIdx.y, fs = blockIdx.z;
    int c = mt*16 + (t & 15), cpl = t >> 4;
    int cpA = kk*32 + cpl, cpB = cpA + 16;
    float ua[9], va[9], ub[9], vb[9];
    {
        const float* pa1 = w + ((size_t)c*NCH + cpA)*9;
        const float* pb1 = w + ((size_t)c*NCH + cpB)*9;
        const float* pa2 = w + ((size_t)cpA*NCH + c)*9;
        const float* pb2 = w + ((size_t)cpB*NCH + c)*9;
#pragma unroll
        for (int q = 0; q < 9; q++) {
            float w1a = pa1[q], w2a = pa2[q], w1b = pb1[q], w2b = pb2[q];
            ua[q] = w1a - w2a; va[q] = w1a + w2a;
            ub[q] = w1b - w2b; vb[q] = w1b + w2b;
        }
    }
    float s = sig[0];
    int la_ = ((c & 15) + 16*(cpl>>3))*8 + (cpl & 7);
    int lb_ = la_ + 32*8;
    __syncthreads();
    for (int fl = fs*68; fl < fs*68 + 68; fl++) {
        int f = f0 + fl;
        int i = f / 17, jj = f - i * 17;    // f = i*17 + j ordering
        int m_[9];
        m_[0] = (i + jj) & 31;  m_[1] = i;             m_[2] = (i - jj) & 31;
        m_[3] = jj;             m_[4] = 0;             m_[5] = (32 - jj) & 31;
        m_[6] = (jj - i) & 31;  m_[7] = (32 - i) & 31; m_[8] = (64 - i - jj) & 31;
        float ArA = 0.f, AiA = 0.f, ArB = 0.f, AiB = 0.f;
#pragma unroll
        for (int q = 0; q < 9; q++) {
            float2 P = wtab[m_[q]];
            ArA += ua[q] * P.x; AiA += va[q] * P.y;
            ArB += ub[q] * P.x; AiB += vb[q] * P.y;
        }
        lar[la_] = f2bf(s*ArA); lai[la_] = f2bf(s*AiA);
        lar[lb_] = f2bf(s*ArB); lai[lb_] = f2bf(s*AiB);
        __syncthreads();
        size_t bch = (((size_t)fl*8 + kk)*16 + mt)*256;   // uint2 units
        ((uint2*)Afrag)[bch + t] = (t < 128) ? ((const uint2*)lar)[t]
                                             : ((const uint2*)lai)[t - 128];
        __syncthreads();
    }
}

// ---------------- neum1: t = z - A z  (identity term from bf16 z in LDS) ----------------
__global__ __launch_bounds__(256) void neum1(
    const unsigned short* __restrict__ Afrag,
    const unsigned short* __restrict__ BR, const unsigned short* __restrict__ BI,
    unsigned short* __restrict__ outR, unsigned short* __restrict__ outI, int f0)
{
    __shared__ uint4 lz[2][1024];   // 32 KB, swizzled
    int fl = blockIdx.x >> 1, half = blockIdx.x & 1;
    int f = f0 + fl;
    int t = threadIdx.x;
    const uint4* s0 = (const uint4*)(BR + (size_t)f*8192);
    const uint4* s1 = (const uint4*)(BI + (size_t)f*8192);
    for (int u = t; u < 1024; u += 256) {
        int b = u >> 5, o16 = u & 31;
        int du = b*32 + (o16 ^ (b & 7));
        lz[0][du] = s0[u];
        lz[1][du] = s1[u];
    }
    __syncthreads();
    int w = t >> 6, lane = t & 63, lo = lane & 15, hi = lane >> 4;
    f32x4 accr[2][2], acci[2][2];
    f32x4 zz = {0.f, 0.f, 0.f, 0.f};
#pragma unroll
    for (int mt = 0; mt < 2; mt++)
#pragma unroll
        for (int nt = 0; nt < 2; nt++) { accr[mt][nt] = zz; acci[mt][nt] = zz; }
    const uint4* A4 = (const uint4*)Afrag;
    for (int kk = 0; kk < 8; kk++) {
        bf16x8 ar[2], ai[2], ain[2];
#pragma unroll
        for (int mt = 0; mt < 2; mt++) {
            int mtg = half*8 + w*2 + mt;
            size_t idx = ((((size_t)fl*8 + kk)*16 + mtg)*2)*64 + lane;
            uint4 va = A4[idx], vb = A4[idx + 64];
            ar[mt] = __builtin_bit_cast(bf16x8, va);
            ai[mt] = __builtin_bit_cast(bf16x8, vb);
            uint4 vn = make_uint4(vb.x ^ 0x80008000u, vb.y ^ 0x80008000u,
                                  vb.z ^ 0x80008000u, vb.w ^ 0x80008000u);
            ain[mt] = __builtin_bit_cast(bf16x8, vn);
        }
        bf16x8 zr[2], zi_[2];
#pragma unroll
        for (int nt = 0; nt < 2; nt++) {
            int b = nt*16 + lo;
            int du = b*32 + ((kk*4 + hi) ^ (b & 7));
            zr[nt]  = __builtin_bit_cast(bf16x8, lz[0][du]);
            zi_[nt] = __builtin_bit_cast(bf16x8, lz[1][du]);
        }
#pragma unroll
        for (int mt = 0; mt < 2; mt++)
#pragma unroll
            for (int nt = 0; nt < 2; nt++) {
                accr[mt][nt] = __builtin_amdgcn_mfma_f32_16x16x32_bf16(ar[mt],  zr[nt],  accr[mt][nt], 0, 0, 0);
                accr[mt][nt] = __builtin_amdgcn_mfma_f32_16x16x32_bf16(ain[mt], zi_[nt], accr[mt][nt], 0, 0, 0);
                acci[mt][nt] = __builtin_amdgcn_mfma_f32_16x16x32_bf16(ar[mt],  zi_[nt], acci[mt][nt], 0, 0, 0);
                acci[mt][nt] = __builtin_amdgcn_mfma_f32_16x16x32_bf16(ai[mt],  zr[nt],  acci[mt][nt], 0, 0, 0);
            }
    }
#pragma unroll
    for (int mt = 0; mt < 2; mt++)
#pragma unroll
        for (int nt = 0; nt < 2; nt++) {
            int c0 = half*128 + w*32 + mt*16 + hi*4;
            int b  = nt*16 + lo;
            // bf16 z from LDS (identity term)
            int o16c = c0 >> 3;
            int duc = b*32 + (o16c ^ (b & 7));
            int sel = (c0 >> 2) & 1;
            uint2 pzr = ((const uint2*)&lz[0][duc])[sel];
            uint2 pzi = ((const uint2*)&lz[1][duc])[sel];
            float zfr[4] = { bf2f(pzr.x & 0xffffu), bf2f(pzr.x >> 16),
                             bf2f(pzr.y & 0xffffu), bf2f(pzr.y >> 16) };
            float zfi[4] = { bf2f(pzi.x & 0xffffu), bf2f(pzi.x >> 16),
                             bf2f(pzi.y & 0xffffu), bf2f(pzi.y >> 16) };
            size_t zb = ((size_t)f*NB + b)*NCH + c0;
            float vr[4], vi[4];
#pragma unroll
            for (int jj = 0; jj < 4; jj++) {
                vr[jj] = zfr[jj] - accr[mt][nt][jj];
                vi[jj] = zfi[jj] - acci[mt][nt][jj];
            }
            *(uint2*)(outR + zb) = make_uint2(pack2(vr[0], vr[1]), pack2(vr[2], vr[3]));
            *(uint2*)(outI + zb) = make_uint2(pack2(vi[0], vi[1]), pack2(vi[2], vi[3]));
        }
}

// ---------------- neum2h: wx = z32 - 2 A t  ->  wxh = H wx  (fused, full f per block) ----------------
__global__ __launch_bounds__(512) void neum2h(
    const unsigned short* __restrict__ Afrag,
    const unsigned short* __restrict__ Hfrag,
    const unsigned short* __restrict__ TR, const unsigned short* __restrict__ TI,
    const float* __restrict__ z32r, const float* __restrict__ z32i,
    float2* __restrict__ wxh, int f0)
{
    __shared__ uint4 lz[2][1024];   // 32 KB: stages t (B-operand), then reused for wx
    int fl = blockIdx.x;
    int f = f0 + fl;
    int t = threadIdx.x;
    const uint4* s0 = (const uint4*)(TR + (size_t)f*8192);
    const uint4* s1 = (const uint4*)(TI + (size_t)f*8192);
    for (int u = t; u < 2048; u += 512) {
        int p = u >> 10, idx = u & 1023;
        int b = idx >> 5, o16 = idx & 31;
        lz[p][b*32 + (o16 ^ (b & 7))] = (p ? s1 : s0)[idx];
    }
    __syncthreads();
    int w = t >> 6, lane = t & 63, lo = lane & 15, hi = lane >> 4;
    const uint4* A4 = (const uint4*)Afrag;
    const uint4* H4 = (const uint4*)Hfrag;
    f32x4 accr[2][2], acci[2][2];
    f32x4 zz = {0.f, 0.f, 0.f, 0.f};
#pragma unroll
    for (int mt = 0; mt < 2; mt++)
#pragma unroll
        for (int nt = 0; nt < 2; nt++) { accr[mt][nt] = zz; acci[mt][nt] = zz; }
    // ---- matmul 1: acc = A * t ----
    for (int kk = 0; kk < 8; kk++) {
        bf16x8 ar[2], ai[2], ain[2];
#pragma unroll
        for (int mt = 0; mt < 2; mt++) {
            int mtg = w*2 + mt;
            size_t idx = ((((size_t)fl*8 + kk)*16 + mtg)*2)*64 + lane;
            uint4 va = A4[idx], vb = A4[idx + 64];
            ar[mt] = __builtin_bit_cast(bf16x8, va);
            ai[mt] = __builtin_bit_cast(bf16x8, vb);
            uint4 vn = make_uint4(vb.x ^ 0x80008000u, vb.y ^ 0x80008000u,
                                  vb.z ^ 0x80008000u, vb.w ^ 0x80008000u);
            ain[mt] = __builtin_bit_cast(bf16x8, vn);
        }
        bf16x8 zr[2], zi_[2];
#pragma unroll
        for (int nt = 0; nt < 2; nt++) {
            int b = nt*16 + lo;
            int du = b*32 + ((kk*4 + hi) ^ (b & 7));
            zr[nt]  = __builtin_bit_cast(bf16x8, lz[0][du]);
            zi_[nt] = __builtin_bit_cast(bf16x8, lz[1][du]);
        }
#pragma unroll
        for (int mt = 0; mt < 2; mt++)
#pragma unroll
            for (int nt = 0; nt < 2; nt++) {
                accr[mt][nt] = __builtin_amdgcn_mfma_f32_16x16x32_bf16(ar[mt],  zr[nt],  accr[mt][nt], 0, 0, 0);
                accr[mt][nt] = __builtin_amdgcn_mfma_f32_16x16x32_bf16(ain[mt], zi_[nt], accr[mt][nt], 0, 0, 0);
                acci[mt][nt] = __builtin_amdgcn_mfma_f32_16x16x32_bf16(ar[mt],  zi_[nt], acci[mt][nt], 0, 0, 0);
                acci[mt][nt] = __builtin_amdgcn_mfma_f32_16x16x32_bf16(ai[mt],  zr[nt],  acci[mt][nt], 0, 0, 0);
            }
    }
    __syncthreads();   // all waves done reading t from LDS
    // ---- epilogue 1: wx = z32 - 2 acc; write bf16 wx into LDS ----
#pragma unroll
    for (int mt = 0; mt < 2; mt++)
#pragma unroll
        for (int nt = 0; nt < 2; nt++) {
            int c0 = w*32 + mt*16 + hi*4;
            int b  = nt*16 + lo;
            size_t zb = ((size_t)f*NB + b)*NCH + c0;
            float4 z4r = *(const float4*)(z32r + zb);
            float4 z4i = *(const float4*)(z32i + zb);
            float vr[4] = { z4r.x - 2.f*accr[mt][nt][0], z4r.y - 2.f*accr[mt][nt][1],
                            z4r.z - 2.f*accr[mt][nt][2], z4r.w - 2.f*accr[mt][nt][3] };
            float vi[4] = { z4i.x - 2.f*acci[mt][nt][0], z4i.y - 2.f*acci[mt][nt][1],
                            z4i.z - 2.f*acci[mt][nt][2], z4i.w - 2.f*acci[mt][nt][3] };
            int o16c = c0 >> 3;
            int duc = b*32 + (o16c ^ (b & 7));
            int sel = (c0 >> 2) & 1;
            ((uint2*)&lz[0][duc])[sel] = make_uint2(pack2(vr[0], vr[1]), pack2(vr[2], vr[3]));
            ((uint2*)&lz[1][duc])[sel] = make_uint2(pack2(vi[0], vi[1]), pack2(vi[2], vi[3]));
        }
    __syncthreads();
    // ---- matmul 2: wxh = H * wx ----
#pragma unroll
    for (int mt = 0; mt < 2; mt++)
#pragma unroll
        for (int nt = 0; nt < 2; nt++) { accr[mt][nt] = zz; acci[mt][nt] = zz; }
    for (int kk = 0; kk < 8; kk++) {
        bf16x8 hm[2];
#pragma unroll
        for (int mt = 0; mt < 2; mt++) {
            int mtg = w*2 + mt;
            hm[mt] = __builtin_bit_cast(bf16x8, H4[((size_t)kk*16 + mtg)*64 + lane]);
        }
        bf16x8 zr[2], zi_[2];
#pragma unroll
        for (int nt = 0; nt < 2; nt++) {
            int b = nt*16 + lo;
            int du = b*32 + ((kk*4 + hi) ^ (b & 7));
            zr[nt]  = __builtin_bit_cast(bf16x8, lz[0][du]);
            zi_[nt] = __builtin_bit_cast(bf16x8, lz[1][du]);
        }
#pragma unroll
        for (int mt = 0; mt < 2; mt++)
#pragma unroll
            for (int nt = 0; nt < 2; nt++) {
                accr[mt][nt] = __builtin_amdgcn_mfma_f32_16x16x32_bf16(hm[mt], zr[nt],  accr[mt][nt], 0, 0, 0);
                acci[mt][nt] = __builtin_amdgcn_mfma_f32_16x16x32_bf16(hm[mt], zi_[nt], acci[mt][nt], 0, 0, 0);
            }
    }
#pragma unroll
    for (int mt = 0; mt < 2; mt++)
#pragma unroll
        for (int nt = 0; nt < 2; nt++) {
            int o0 = w*32 + mt*16 + hi*4;
            int b  = nt*16 + lo;
#pragma unroll
            for (int jj = 0; jj < 4; jj++) {
                wxh[((size_t)f*NCH + o0 + jj)*NB + b] =
                    make_float2(accr[mt][nt][jj], acci[mt][nt][jj]);
            }
        }
}

// ---------------- pass I: complex ifft along i -> G[j][r][ob] (coalesced stores) ----------------
template<int RH>
__device__ __forceinline__ void ifft_i_body(const float2* __restrict__ wxh,
                                            float2* __restrict__ G, int j, int ob)
{
    float2 Gacc[16];
#pragma unroll
    for (int rr = 0; rr < 16; rr++) Gacc[rr] = make_float2(0.f, 0.f);
#pragma unroll
    for (int i = 0; i < 32; i++) {
        float2 Y = wxh[((size_t)(i * 17 + j)) * 8192 + ob];
#pragma unroll
        for (int rr = 0; rr < 16; rr++) {
            int m = (i * (RH * 16 + rr)) & 31;     // compile-time constant
            Gacc[rr].x += Y.x*COS32[m] - Y.y*SIN32[m];
            Gacc[rr].y += Y.x*SIN32[m] + Y.y*COS32[m];
        }
    }
#pragma unroll
    for (int rr = 0; rr < 16; rr++) {
        G[((size_t)(j*32 + RH*16 + rr))*8192 + ob] =
            make_float2(Gacc[rr].x * (1.f/32.f), Gacc[rr].y * (1.f/32.f));
    }
}

__global__ __launch_bounds__(256) void ifft_i(const float2* __restrict__ wxh, float2* __restrict__ G) {
    int bid = blockIdx.x;
    int j   = bid >> 6;          // 0..16
    int rh  = (bid >> 5) & 1;    // 0..1
    int obc = bid & 31;          // 0..31
    int ob  = obc * 256 + threadIdx.x;
    if (rh == 0) ifft_i_body<0>(wxh, G, j, ob);
    else         ifft_i_body<1>(wxh, G, j, ob);
}

// ---------------- pass II: irfft along j + bias -> out[b][o][r][s] ----------------
__global__ __launch_bounds__(256) void irfft_j(const float2* __restrict__ G,
                                               const float* __restrict__ bias,
                                               float* __restrict__ out) {
    int gid = blockIdx.x * 256 + threadIdx.x;
    int r = gid >> 13, ob = gid & 8191;
    int o = ob >> 5, b = ob & 31;
    float2 Gv[17];
#pragma unroll
    for (int jj = 0; jj < 17; jj++)
        Gv[jj] = G[((size_t)(jj*32 + r))*8192 + ob];
    float y[32];
    float g0 = Gv[0].x, g16 = Gv[16].x;
#pragma unroll
    for (int s = 0; s < 32; s++) y[s] = g0 + ((s & 1) ? -g16 : g16);
#pragma unroll
    for (int jj = 1; jj < 16; jj++) {
#pragma unroll
        for (int s = 0; s < 32; s++) {
            int m = (jj * s) & 31;                 // compile-time constant
            y[s] += 2.f * (Gv[jj].x * COS32[m] - Gv[jj].y * SIN32[m]);
        }
    }
    float bv = bias[o];
    float* op = out + ((size_t)(b * NCH + o) * 32 + r) * 32;
#pragma unroll
    for (int s = 0; s < 32; s++) op[s] = y[s] * (1.f/32.f) + bv;
}

extern "C" void kernel_launch(void* const* d_in, const int* in_sizes, int n_in,
                              void* d_out, int out_size, void* d_ws, size_t ws_size,
                              hipStream_t stream) {
    (void)in_sizes; (void)n_in; (void)out_size;
    if (ws_size < WS_NEED) return;

    const float* x     = (const float*)d_in[0];
    const float* w     = (const float*)d_in[1];
    const float* alpha = (const float*)d_in[2];
    const float* H     = (const float*)d_in[3];
    const float* bias  = (const float*)d_in[4];
    float* out = (float*)d_out;

    char* ws = (char*)d_ws;
    unsigned short* Afrag = (unsigned short*)(ws + OFF_AFRAG);
    unsigned short* zbr   = (unsigned short*)(ws + OFF_ZBR);
    unsigned short* zbi   = (unsigned short*)(ws + OFF_ZBI);
    unsigned short* tbr   = (unsigned short*)(ws + OFF_TBR);
    unsigned short* tbi   = (unsigned short*)(ws + OFF_TBI);
    float* z32r = (float*)(ws + OFF_Z32R);
    float* z32i = (float*)(ws + OFF_Z32I);
    float2* wxh = (float2*)(ws + OFF_WXH);   // aliases tmp
    float2* tmp = (float2*)(ws + OFF_WXH);
    float2* G   = (float2*)(ws + OFF_AFRAG); // aliases Afrag (dead after passes)
    unsigned short* Hfrag = (unsigned short*)(ws + OFF_HFRAG);
    float* red = (float*)(ws + OFF_RED);
    float* sig = red + 256;

    norm_part<<<256, 256, 0, stream>>>(w, red);
    norm_final<<<1, 256, 0, stream>>>(red, alpha, sig);
    hfrag_build<<<dim3(8, 16), 64, 0, stream>>>(H, Hfrag);

    rfft2_reg<<<1024, 256, 0, stream>>>(x, tmp);
    transpose_z<<<dim3(8, 17, 32), 256, 0, stream>>>(tmp, z32r, z32i, zbr, zbi);

    for (int ch = 0; ch < 2; ch++) {
        int f0 = ch * FPC;
        a_build_frag<<<dim3(16, 8, 4), 256, 0, stream>>>(w, sig, Afrag, f0);
        neum1<<<FPC*2, 256, 0, stream>>>(Afrag, zbr, zbi, tbr, tbi, f0);
        neum2h<<<FPC, 512, 0, stream>>>(Afrag, Hfrag, tbr, tbi, z32r, z32i, wxh, f0);
    }

    ifft_i<<<1088, 256, 0, stream>>>(wxh, G);
    irfft_j<<<1024, 256, 0, stream>>>(G, bias, out);
}